// Round 13
// baseline (498.037 us; speedup 1.0000x reference)
//
#include <hip/hip_runtime.h>
#include <hip/hip_bf16.h>
#include <math.h>

// ---- workspace layout (float offsets) ----
static const size_t OFF_Q     = 0;          // [512][256] f32
static const size_t OFF_GQ    = 131072;     // [512][256] f32
static const size_t OFF_GR    = 262144;     // [512][256] f32
static const size_t OFF_RPRE  = 393216;     // [512][256] f32
static const size_t OFF_QBF   = 524288;     // [512][256] bf16 (65536 f32 slots)
static const size_t OFF_WKBF  = 8978432;    // [256][256] bf16 (32768 slots)
static const size_t OFF_WVBF  = 9011200;    // [256][256] bf16 (32768 slots)
static const size_t OFF_KB    = 9043968;    // [65536][256] bf16 (8388608 slots)
static const size_t OFF_ZP    = 17432576;   // [4][512][64] f32 (Z partials)
static const size_t OFF_AMV   = 17698816;   // [64][512][2] f32
static const size_t OFF_AMI   = 17764352;   // [64][512][2] i32
static const size_t OFF_MX    = 17829888;   // [512] i32
static const size_t OFF_UMX   = 17830400;   // [512] f32
static const size_t OFF_CANDV = 17830912;   // [2048] f32
static const size_t OFF_CANDI = 17835008;   // [2048] i32
static const size_t OFF_BSUM  = 17839104;   // [256] f32
static const size_t OFF_CNT   = 17839360;   // [16] i32
static const size_t OFF_IDXA  = 17839376;   // [512] i32
static const size_t OFF_CHAIN = 17839888;   // [512] i32

typedef short v8s __attribute__((ext_vector_type(8)));
typedef float f32x4 __attribute__((ext_vector_type(4)));

__device__ __forceinline__ unsigned short f2bf(float f) {
  unsigned int x = __float_as_uint(f);
  unsigned int r = (x + 0x7fffu + ((x >> 16) & 1u)) >> 16;
  return (unsigned short)r;
}

// async global->LDS DMA, 16 B per lane; LDS dest = wave-uniform base + lane*16
__device__ __forceinline__ void gld16(const void* g, void* l) {
  __builtin_amdgcn_global_load_lds(
      (const __attribute__((address_space(1))) void*)g,
      (__attribute__((address_space(3))) void*)l, 16, 0, 0);
}

// ============ cvt: fp32 -> bf16 (8 elems/thread) — weights only ============
__global__ void k_cvt(const float* __restrict__ in, unsigned short* __restrict__ out, int n) {
  int i = (blockIdx.x * 256 + threadIdx.x) * 8;
  if (i + 8 <= n) {
    float4 a = *reinterpret_cast<const float4*>(in + i);
    float4 b = *reinterpret_cast<const float4*>(in + i + 4);
    ushort4 o1 = {f2bf(a.x), f2bf(a.y), f2bf(a.z), f2bf(a.w)};
    ushort4 o2 = {f2bf(b.x), f2bf(b.y), f2bf(b.z), f2bf(b.w)};
    *reinterpret_cast<ushort4*>(out + i) = o1;
    *reinterpret_cast<ushort4*>(out + i + 4) = o2;
  }
}

// ============ PROJQ: blocks 0..1023 = MFMA K/V projection; 1024..1535 = Q/Gq GEMVs ============
__global__ __launch_bounds__(256) void k_projq(const float* __restrict__ mem,
    const unsigned short* __restrict__ Wkbf, const float* __restrict__ bk,
    const unsigned short* __restrict__ Wvbf, const float* __restrict__ bv,
    unsigned short* __restrict__ Kout, unsigned short* __restrict__ Vt,
    const float* __restrict__ query, const float* __restrict__ Wq,
    const float* __restrict__ bq, const float* __restrict__ Wg,
    const float* __restrict__ bg, float* __restrict__ Q,
    float* __restrict__ Gq, unsigned short* __restrict__ Qbf) {
  __shared__ __align__(16) char sbuf[36864];
  const int bid = blockIdx.x;
  const int t = threadIdx.x;

  if (bid >= 1024) {
    float* qrow = reinterpret_cast<float*>(sbuf);
    const int i = bid - 1024;
    const int d = t;
    qrow[d] = query[(size_t)i * 256 + d];
    __syncthreads();
    const float4* wq = reinterpret_cast<const float4*>(Wq + (size_t)d * 256);
    float acc = 0.f;
#pragma unroll 8
    for (int j4 = 0; j4 < 64; ++j4) {
      float4 w = wq[j4];
      float4 q = *reinterpret_cast<const float4*>(&qrow[j4 * 4]);
      acc += w.x * q.x + w.y * q.y + w.z * q.z + w.w * q.w;
    }
    float qv = acc + bq[d];
    Q[(size_t)i * 256 + d] = qv;
    Qbf[(size_t)i * 256 + d] = f2bf(qv * 0.125f);
    const float4* wg = reinterpret_cast<const float4*>(Wg + (size_t)d * 768);
    float acc2 = 0.f;
#pragma unroll 8
    for (int j4 = 0; j4 < 64; ++j4) {
      float4 w = wg[j4];
      float4 q = *reinterpret_cast<const float4*>(&qrow[j4 * 4]);
      acc2 += w.x * q.x + w.y * q.y + w.z * q.z + w.w * q.w;
    }
    Gq[(size_t)i * 256 + d] = acc2 + bg[d];
    return;
  }

  const int w = t >> 6, l = t & 63, l15 = l & 15, lg = l >> 4;
  const int mb = bid * 64;
  const int mrow = mb + w * 16 + l15;
  v8s am[8];
#pragma unroll
  for (int kk = 0; kk < 8; ++kk) {
    const float* src = mem + (size_t)mrow * 256 + kk * 32 + lg * 8;
    float4 f0 = *reinterpret_cast<const float4*>(src);
    float4 f1 = *reinterpret_cast<const float4*>(src + 4);
    v8s a;
    a[0] = (short)f2bf(f0.x); a[1] = (short)f2bf(f0.y);
    a[2] = (short)f2bf(f0.z); a[3] = (short)f2bf(f0.w);
    a[4] = (short)f2bf(f1.x); a[5] = (short)f2bf(f1.y);
    a[6] = (short)f2bf(f1.z); a[7] = (short)f2bf(f1.w);
    am[kk] = a;
  }

#define STAGE_W(Wsrc, dt)                                                     \
  {                                                                           \
    _Pragma("unroll")                                                         \
    for (int j = 0; j < 8; ++j) {                                             \
      int off = j * 4096 + w * 1024 + l * 16;                                 \
      int row = off >> 9;                                                     \
      int col = off & 511;                                                    \
      gld16(reinterpret_cast<const char*>(Wsrc) +                             \
                (size_t)((dt) * 64 + row) * 512 + (col ^ ((row & 7) << 4)),   \
            sbuf + j * 4096 + w * 1024);                                      \
    }                                                                         \
  }

  // ---- K = mem @ Wk^T + bk ----
  {
    f32x4 acc[16];
#pragma unroll
    for (int df = 0; df < 16; ++df) {
      float bz = bk[df * 16 + l15];
      acc[df] = (f32x4){bz, bz, bz, bz};
    }
    for (int dt = 0; dt < 4; ++dt) {
      STAGE_W(Wkbf, dt);
      asm volatile("s_waitcnt vmcnt(0)" ::: "memory");
      __builtin_amdgcn_s_barrier();
#pragma unroll
      for (int kk = 0; kk < 8; ++kk)
#pragma unroll
        for (int dfl = 0; dfl < 4; ++dfl) {
          const int row = dfl * 16 + l15;
          const v8s b = *reinterpret_cast<const v8s*>(
              sbuf + row * 512 + ((kk * 64 + lg * 16) ^ ((row & 7) << 4)));
          acc[dt * 4 + dfl] =
              __builtin_amdgcn_mfma_f32_16x16x32_bf16(am[kk], b, acc[dt * 4 + dfl], 0, 0, 0);
        }
      asm volatile("" ::: "memory");
      __builtin_amdgcn_s_barrier();
    }
    unsigned short* bounce = reinterpret_cast<unsigned short*>(sbuf);
#pragma unroll
    for (int df = 0; df < 16; ++df)
#pragma unroll
      for (int r = 0; r < 4; ++r)
        bounce[(w * 16 + lg * 4 + r) * 264 + df * 16 + l15] = f2bf(acc[df][r]);
  }
  __syncthreads();
  {
    unsigned short* bounce = reinterpret_cast<unsigned short*>(sbuf);
    int row = t >> 2, quad = t & 3;
    const uint4* src = reinterpret_cast<const uint4*>(&bounce[row * 264 + quad * 64]);
    uint4* dst = reinterpret_cast<uint4*>(Kout + (size_t)(mb + row) * 256 + quad * 64);
#pragma unroll
    for (int x = 0; x < 8; ++x) dst[x] = src[x];
  }
  __syncthreads();
  // ---- V = mem @ Wv^T + bv, stored transposed Vt[d][m] ----
  {
    f32x4 acc[16];
#pragma unroll
    for (int df = 0; df < 16; ++df) {
      float bz = bv[df * 16 + l15];
      acc[df] = (f32x4){bz, bz, bz, bz};
    }
    for (int dt = 0; dt < 4; ++dt) {
      STAGE_W(Wvbf, dt);
      asm volatile("s_waitcnt vmcnt(0)" ::: "memory");
      __builtin_amdgcn_s_barrier();
#pragma unroll
      for (int kk = 0; kk < 8; ++kk)
#pragma unroll
        for (int dfl = 0; dfl < 4; ++dfl) {
          const int row = dfl * 16 + l15;
          const v8s b = *reinterpret_cast<const v8s*>(
              sbuf + row * 512 + ((kk * 64 + lg * 16) ^ ((row & 7) << 4)));
          acc[dt * 4 + dfl] =
              __builtin_amdgcn_mfma_f32_16x16x32_bf16(am[kk], b, acc[dt * 4 + dfl], 0, 0, 0);
        }
      asm volatile("" ::: "memory");
      __builtin_amdgcn_s_barrier();
    }
    unsigned short* bounce = reinterpret_cast<unsigned short*>(sbuf);
#pragma unroll
    for (int df = 0; df < 16; ++df)
#pragma unroll
      for (int r = 0; r < 4; ++r)
        bounce[(df * 16 + l15) * 72 + w * 16 + lg * 4 + r] = f2bf(acc[df][r]);
  }
  __syncthreads();
  {
    const unsigned short* bounce = reinterpret_cast<const unsigned short*>(sbuf);
    const uint4* src = reinterpret_cast<const uint4*>(&bounce[t * 72]);
    uint4* dst = reinterpret_cast<uint4*>(Vt + (size_t)t * 65536 + mb);
#pragma unroll
    for (int x = 0; x < 8; ++x) dst[x] = src[x];
  }
#undef STAGE_W
}

// ============ FUSED pass v2: single-K buffer (mid-iter prefetch) + dbuf V  ============
// LDS 54272 B -> 3 blocks/CU. K(mt+1) issued after last K(mt) read; hides under PV.
__global__ __launch_bounds__(256, 3) void k_fused(const unsigned short* __restrict__ Qbf,
    const unsigned short* __restrict__ Kb, const unsigned short* __restrict__ Vt,
    float* __restrict__ part2, float* __restrict__ zpart,
    float* __restrict__ amv, int* __restrict__ ami) {
  __shared__ __align__(16) unsigned short Ks[8192];        // 16 KB, single
  __shared__ __align__(16) unsigned short VsBuf[2][8192];  // 32 KB, double
  __shared__ __align__(16) unsigned short Pl[4][16][40];   // 5 KB
  const int mc = blockIdx.x;   // 0..63
  const int qc = blockIdx.y;   // 0..7
  const int t = threadIdx.x;
  const int w = t >> 6, l = t & 63, l15 = l & 15, lg = l >> 4;
  const int qbase = qc * 64 + w * 16;
  const char* Kbc = reinterpret_cast<const char*>(Kb);
  const char* Vtc = reinterpret_cast<const char*>(Vt);
  char* lds_k = reinterpret_cast<char*>(Ks);
  char* lds_v = reinterpret_cast<char*>(VsBuf);
  v8s aq[4][2];
#pragma unroll
  for (int h = 0; h < 4; ++h)
#pragma unroll
    for (int kk = 0; kk < 2; ++kk)
      aq[h][kk] = *reinterpret_cast<const v8s*>(
          Qbf + (size_t)(qbase + l15) * 256 + h * 64 + kk * 32 + lg * 8);
  f32x4 racc[4][4] = {};
  float zs[4][4] = {};
  float v1[4], v2[4]; int i1[4], i2[4];
#pragma unroll
  for (int r = 0; r < 4; ++r) { v1[r] = -INFINITY; v2[r] = -INFINITY; i1[r] = 0x7fffffff; i2[r] = 0x7fffffff; }
  const int mbase = mc * 1024;

#define STAGE_K2(m0)                                                          \
  {                                                                           \
    _Pragma("unroll")                                                         \
    for (int j = 0; j < 4; ++j) {                                             \
      int off = w * 4096 + j * 1024 + l * 16;                                 \
      int row = off >> 9;                                                     \
      int col = off & 511;                                                    \
      gld16(Kbc + (size_t)((m0) + row) * 512 + (col ^ ((row & 7) << 4)),      \
            lds_k + w * 4096 + j * 1024);                                     \
    }                                                                         \
  }
#define STAGE_V2(bufsel, m0)                                                  \
  {                                                                           \
    _Pragma("unroll")                                                         \
    for (int j = 0; j < 4; ++j) {                                             \
      int off = w * 4096 + j * 1024 + l * 16;                                 \
      int row = off >> 6;                                                     \
      int col = off & 63;                                                     \
      gld16(Vtc + (size_t)row * 131072 + (size_t)(m0) * 2 +                   \
                (col ^ (((row >> 1) & 3) << 4)),                              \
            lds_v + (bufsel) * 16384 + w * 4096 + j * 1024);                  \
    }                                                                         \
  }

  // prologue: V(0) then K(0)  (order matters for vmcnt accounting)
  STAGE_V2(0, mbase);
  STAGE_K2(mbase);
  for (int mt = 0; mt < 32; ++mt) {
    const int m0 = mbase + mt * 32;
    if (mt < 31) {
      STAGE_V2((mt + 1) & 1, m0 + 32);   // V prefetch into other buffer
      // outstanding (old->new): V(mt), K(mt), V(mt+1) -> wait V(mt),K(mt)
      asm volatile("s_waitcnt vmcnt(4)" ::: "memory");
    } else {
      asm volatile("s_waitcnt vmcnt(0)" ::: "memory");
    }
    __builtin_amdgcn_s_barrier();
    const char* vbp = lds_v + (mt & 1) * 16384;
    float cacc[4][2] = {};
    f32x4 sacc[4][2];
    // ---- phase 1: scores for all heads (K reads complete after this) ----
#pragma unroll
    for (int h = 0; h < 4; ++h)
#pragma unroll
      for (int nf = 0; nf < 2; ++nf) {
        const int row = nf * 16 + l15;
        const int sw = (row & 7) << 4;
        f32x4 acc = {};
#pragma unroll
        for (int kk = 0; kk < 2; ++kk) {
          const v8s b = *reinterpret_cast<const v8s*>(
              lds_k + row * 512 + ((h * 128 + kk * 64 + lg * 16) ^ sw));
          acc = __builtin_amdgcn_mfma_f32_16x16x32_bf16(aq[h][kk], b, acc, 0, 0, 0);
        }
        sacc[h][nf] = acc;
      }
    asm volatile("" ::: "memory");
    __builtin_amdgcn_s_barrier();        // all waves done reading K(mt)
    if (mt < 31) {
      STAGE_K2(m0 + 32);                 // K(mt+1) into the single buffer; lands during PV
    }
    // ---- phase 2: exp + Pl + PV per head ----
#pragma unroll
    for (int h = 0; h < 4; ++h) {
#pragma unroll
      for (int nf = 0; nf < 2; ++nf)
#pragma unroll
        for (int r = 0; r < 4; ++r) {
          float e = __expf(sacc[h][nf][r]);
          cacc[r][nf] += e;
          zs[r][h] += e;
          Pl[w][lg * 4 + r][nf * 16 + l15] =
              (unsigned short)(__float_as_uint(e) >> 16);
        }
      const v8s pa = *reinterpret_cast<const v8s*>(
          reinterpret_cast<const char*>(&Pl[w][l15][0]) + lg * 16);
#pragma unroll
      for (int df = 0; df < 4; ++df) {
        const int vrow = h * 64 + df * 16 + l15;
        const v8s vb = *reinterpret_cast<const v8s*>(
            vbp + vrow * 64 + ((lg * 16) ^ (((vrow >> 1) & 3) << 4)));
        racc[h][df] = __builtin_amdgcn_mfma_f32_16x16x32_bf16(pa, vb, racc[h][df], 0, 0, 0);
      }
    }
#pragma unroll
    for (int r = 0; r < 4; ++r)
#pragma unroll
      for (int nf = 0; nf < 2; ++nf) {
        float val = cacc[r][nf];
        int idx = m0 + nf * 16 + l15;
        if (val > v1[r] || (val == v1[r] && idx < i1[r])) {
          v2[r] = v1[r]; i2[r] = i1[r]; v1[r] = val; i1[r] = idx;
        } else if (val > v2[r] || (val == v2[r] && idx < i2[r])) {
          v2[r] = val; i2[r] = idx;
        }
      }
    asm volatile("" ::: "memory");
    __builtin_amdgcn_s_barrier();        // all waves done reading V(mt) before next V stage
  }
#undef STAGE_K2
#undef STAGE_V2
#pragma unroll
  for (int h = 0; h < 4; ++h)
#pragma unroll
    for (int df = 0; df < 4; ++df)
#pragma unroll
      for (int r = 0; r < 4; ++r) {
        int q = qbase + lg * 4 + r;
        part2[(size_t)mc * 131072 + (size_t)q * 256 + h * 64 + df * 16 + l15] = racc[h][df][r];
      }
#pragma unroll
  for (int mask = 1; mask <= 8; mask <<= 1)
#pragma unroll
    for (int r = 0; r < 4; ++r)
#pragma unroll
      for (int h = 0; h < 4; ++h)
        zs[r][h] += __shfl_xor(zs[r][h], mask);
  if (l15 == 0) {
#pragma unroll
    for (int r = 0; r < 4; ++r)
#pragma unroll
      for (int h = 0; h < 4; ++h) {
        int q = qbase + lg * 4 + r;
        zpart[((size_t)h * 512 + q) * 64 + mc] = zs[r][h];
      }
  }
#pragma unroll
  for (int mask = 1; mask <= 8; mask <<= 1) {
#pragma unroll
    for (int r = 0; r < 4; ++r) {
      float ov1 = __shfl_xor(v1[r], mask); int oi1 = __shfl_xor(i1[r], mask);
      float ov2 = __shfl_xor(v2[r], mask); int oi2 = __shfl_xor(i2[r], mask);
      bool cGTa = ov1 > v1[r] || (ov1 == v1[r] && oi1 < i1[r]);
      float nv1, nv2; int ni1, ni2;
      if (cGTa) {
        nv1 = ov1; ni1 = oi1;
        bool aGTd = v1[r] > ov2 || (v1[r] == ov2 && i1[r] < oi2);
        nv2 = aGTd ? v1[r] : ov2; ni2 = aGTd ? i1[r] : oi2;
      } else {
        nv1 = v1[r]; ni1 = i1[r];
        bool bGTc = v2[r] > ov1 || (v2[r] == ov1 && i2[r] < oi1);
        nv2 = bGTc ? v2[r] : ov1; ni2 = bGTc ? i2[r] : oi1;
      }
      v1[r] = nv1; i1[r] = ni1; v2[r] = nv2; i2[r] = ni2;
    }
  }
  if (l15 == 0) {
#pragma unroll
    for (int r = 0; r < 4; ++r) {
      int q = qbase + lg * 4 + r;
      amv[((size_t)mc * 512 + q) * 2] = v1[r];
      amv[((size_t)mc * 512 + q) * 2 + 1] = v2[r];
      ami[((size_t)mc * 512 + q) * 2] = i1[r];
      ami[((size_t)mc * 512 + q) * 2 + 1] = i2[r];
    }
  }
}

// ============ PAR0: amax2 (0..511) | cand (512..767) | rcomb+Z (768..1279) ============
__global__ __launch_bounds__(256) void k_par0(const float* __restrict__ Qf,
    const float* __restrict__ Wk, const float* __restrict__ bk,
    const float* __restrict__ memory, const float* __restrict__ zpart,
    const float* __restrict__ amv, const int* __restrict__ ami,
    const float* __restrict__ usage, int* __restrict__ mx, float* __restrict__ umx,
    float* __restrict__ candv, int* __restrict__ candi, int* __restrict__ cnt,
    float* __restrict__ bsum, const float* __restrict__ part2,
    float* __restrict__ rpre) {
  __shared__ float u[4][256];
  __shared__ float ch[4];
  __shared__ float qrow[256];
  __shared__ float redv[4];
  __shared__ int redi[4];
  __shared__ float zish[4];
  const int bid = blockIdx.x;
  const int t = threadIdx.x;

  if (bid >= 768) {
    const int b = bid - 768;
    const int h = t >> 6, c = t & 63;
    float z = zpart[((size_t)h * 512 + b) * 64 + c];
#pragma unroll
    for (int mask = 32; mask >= 1; mask >>= 1) z += __shfl_xor(z, mask);
    const float iZ = 1.0f / z;
    const int d = t;
    float s = 0.f;
    for (int cc = 0; cc < 64; ++cc) s += part2[(size_t)cc * 131072 + (size_t)b * 256 + d];
    rpre[(size_t)b * 256 + d] = s * iZ;
    return;
  }
  if (bid >= 512) {
    float* sred = qrow;
    int g = (bid - 512) * 256 + t;
    float uu = usage[g];
    sred[t] = uu;
    __syncthreads();
    for (int s = 128; s > 0; s >>= 1) {
      if (t < s) sred[t] += sred[t + s];
      __syncthreads();
    }
    if (t == 0) bsum[bid - 512] = sred[0];
    if (uu < 0.25f) {
      int pos = atomicAdd(cnt, 1);
      if (pos < 2048) { candv[pos] = uu; candi[pos] = g; }
    }
    return;
  }

  const int row = bid;
  {
    const int h = t >> 6, c = t & 63;
    float z = zpart[((size_t)h * 512 + row) * 64 + c];
#pragma unroll
    for (int mask = 32; mask >= 1; mask >>= 1) z += __shfl_xor(z, mask);
    if (c == 0) zish[h] = 1.0f / z;
  }
  qrow[t] = Qf[(size_t)row * 256 + t];
  __syncthreads();
#pragma unroll
  for (int h = 0; h < 4; ++h) {
    float s = 0.f;
    for (int d = 0; d < 64; ++d) s += qrow[h * 64 + d] * Wk[(size_t)(h * 64 + d) * 256 + t];
    u[h][t] = s;
  }
  if (t < 4) {
    float s = 0.f;
    for (int d = 0; d < 64; ++d) s += qrow[t * 64 + d] * bk[t * 64 + d];
    ch[t] = s;
  }
  __syncthreads();
  const int wv = t >> 6, ln = t & 63;
  const float Zi0 = zish[0], Zi1 = zish[1], Zi2 = zish[2], Zi3 = zish[3];
  float bestv = -INFINITY; int besti = 0x7fffffff;
  for (int c = wv; c < 128; c += 4) {
    int m = ami[((size_t)(c >> 1) * 512 + row) * 2 + (c & 1)];
    float s0 = 0.f, s1 = 0.f, s2 = 0.f, s3 = 0.f;
#pragma unroll
    for (int k = 0; k < 4; ++k) {
      float mv = memory[(size_t)m * 256 + ln + 64 * k];
      s0 += mv * u[0][ln + 64 * k];
      s1 += mv * u[1][ln + 64 * k];
      s2 += mv * u[2][ln + 64 * k];
      s3 += mv * u[3][ln + 64 * k];
    }
#pragma unroll
    for (int mask = 32; mask >= 1; mask >>= 1) {
      s0 += __shfl_xor(s0, mask); s1 += __shfl_xor(s1, mask);
      s2 += __shfl_xor(s2, mask); s3 += __shfl_xor(s3, mask);
    }
    float a = __expf((s0 + ch[0]) * 0.125f) * Zi0 +
              __expf((s1 + ch[1]) * 0.125f) * Zi1 +
              __expf((s2 + ch[2]) * 0.125f) * Zi2 +
              __expf((s3 + ch[3]) * 0.125f) * Zi3;
    if (a > bestv || (a == bestv && m < besti)) { bestv = a; besti = m; }
  }
  if (ln == 0) { redv[wv] = bestv; redi[wv] = besti; }
  __syncthreads();
  if (t == 0) {
    float bv = -INFINITY; int bi = 0x7fffffff;
#pragma unroll
    for (int q = 0; q < 4; ++q) {
      if (redv[q] > bv || (redv[q] == bv && redi[q] < bi)) { bv = redv[q]; bi = redi[q]; }
    }
    mx[row] = bi;
    umx[row] = usage[bi];
  }
}

// ============ PAR1: scan (0) | out1 x4 rows (1..128) | full newmem copy (129..1152) ============
__global__ __launch_bounds__(1024) void k_par1(const float* __restrict__ candv_g,
    const int* __restrict__ candi_g, const int* __restrict__ cnt_g,
    const float* __restrict__ bsum, const int* __restrict__ mx,
    const float* __restrict__ umx, const float* __restrict__ usage,
    int* __restrict__ idxA, int* __restrict__ chainA, float* __restrict__ new_usage,
    const float* __restrict__ rpre, const float* __restrict__ Wo,
    const float* __restrict__ bo, const float* __restrict__ Wg,
    float* __restrict__ retr, float* __restrict__ Gr,
    const float* __restrict__ memory, float* __restrict__ newmem) {
  __shared__ float bV[256 * 24];
  __shared__ int   bI[256 * 24];
  __shared__ unsigned char cnt8[65536];
  __shared__ int si[2048];
  __shared__ unsigned int bmSeen[2048];
  __shared__ unsigned int bmDup[2048];
  __shared__ unsigned int bmCand[2048];
  __shared__ int idxl[512];
  __shared__ int chl[512];
  __shared__ int bcnt[256];
  __shared__ int bpre[256];
  __shared__ double dred[256];
  __shared__ int totsh;

  const int bid = blockIdx.x;
  const int t = threadIdx.x;

  if (bid >= 129) {
    const size_t base = (size_t)(bid - 129) * 16384 + (size_t)t * 16;
#pragma unroll
    for (int j = 0; j < 4; ++j) {
      size_t idx = base + (size_t)j * 4;
      *reinterpret_cast<float4*>(newmem + idx) =
          *reinterpret_cast<const float4*>(memory + idx);
    }
    return;
  }
  if (bid >= 1) {
    float* rr = bV;
    float* rf = bV + 1024;
    const int r4 = t >> 8, d = t & 255;
    const int i = (bid - 1) * 4 + r4;
    rr[r4 * 256 + d] = rpre[(size_t)i * 256 + d];
    __syncthreads();
    const float4* wo = reinterpret_cast<const float4*>(Wo + (size_t)d * 256);
    float acc = 0.f;
#pragma unroll 8
    for (int j4 = 0; j4 < 64; ++j4) {
      float4 w = wo[j4];
      float4 q = *reinterpret_cast<const float4*>(&rr[r4 * 256 + j4 * 4]);
      acc += w.x * q.x + w.y * q.y + w.z * q.z + w.w * q.w;
    }
    float v = acc + bo[d];
    retr[(size_t)i * 256 + d] = v;
    rf[r4 * 256 + d] = v;
    __syncthreads();
    const float4* wg = reinterpret_cast<const float4*>(Wg + (size_t)d * 768 + 512);
    float acc2 = 0.f;
#pragma unroll 8
    for (int j4 = 0; j4 < 64; ++j4) {
      float4 w = wg[j4];
      float4 q = *reinterpret_cast<const float4*>(&rf[r4 * 256 + j4 * 4]);
      acc2 += w.x * q.x + w.y * q.y + w.z * q.z + w.w * q.w;
    }
    Gr[(size_t)i * 256 + d] = acc2;
    return;
  }

  // ---- block 0: selection scan (v4) ----
  const int ncg0 = cnt_g[0];
  const int ncg = ncg0 > 2048 ? 2048 : ncg0;

  for (int p = t; p < 2048; p += 1024) {
    si[p] = 0; bmSeen[p] = 0u; bmDup[p] = 0u; bmCand[p] = 0u;
  }
  {
    uint4 z; z.x = 0u; z.y = 0u; z.z = 0u; z.w = 0u;
    uint4* c4 = reinterpret_cast<uint4*>(cnt8);
#pragma unroll
    for (int r = 0; r < 4; ++r) c4[t + r * 1024] = z;
  }
  if (t < 256) { bcnt[t] = 0; dred[t] = (double)bsum[t]; }
  __syncthreads();
  for (int s = 128; s > 0; s >>= 1) {
    if (t < s) dred[t] += dred[t + s];
    __syncthreads();
  }
  if (t < 512) {
    int m = mx[t];
    unsigned bit = 1u << (m & 31);
    unsigned old = atomicOr(&bmSeen[m >> 5], bit);
    if (old & bit) atomicOr(&bmDup[m >> 5], bit);
  }
  for (int p = t; p < ncg; p += 1024) {
    float v = candv_g[p];
    int ix = candi_g[p];
    atomicOr(&bmCand[ix >> 5], 1u << (ix & 31));
    int b = (int)(v * 1024.0f);
    if (b > 255) b = 255;
    int pos = atomicAdd(&bcnt[b], 1);
    if (pos < 24) { bV[b * 24 + pos] = v; bI[b * 24 + pos] = ix; }
  }
  __syncthreads();
  if (t < 256) {
    int n = bcnt[t]; if (n > 24) n = 24;
    bcnt[t] = n;
    bpre[t] = n;
  }
  __syncthreads();
  for (int s2 = 1; s2 < 256; s2 <<= 1) {
    int add = 0;
    if (t < 256 && t >= s2) add = bpre[t - s2];
    __syncthreads();
    if (t < 256) bpre[t] += add;
    __syncthreads();
  }
  if (t < 256) {
    int n = bcnt[t];
    float* bv = bV + t * 24;
    int* bi = bI + t * 24;
    for (int a = 1; a < n; ++a) {
      float v = bv[a]; int ix = bi[a];
      int p = a - 1;
      while (p >= 0) {
        float vp = bv[p];
        int ip = bi[p];
        if (vp < v || (vp == v && ip < ix)) break;
        bv[p + 1] = vp; bi[p + 1] = ip;
        --p;
      }
      bv[p + 1] = v; bi[p + 1] = ix;
    }
    if (t == 255) totsh = bpre[255];
  }
  __syncthreads();
  if (t < 256) {
    int n = bcnt[t];
    int off = bpre[t] - n;
    for (int k = 0; k < n; ++k) {
      int ix = bI[t * 24 + k];
      int tag = (bmSeen[ix >> 5] >> (ix & 31)) & 1;
      si[off + k] = ix | (tag << 30);
    }
  }
  __syncthreads();
  int nc = totsh;
  if (nc < 1) nc = 1;
  if (t < 64) {
    const int lane = t;
    const double sum0 = dred[0];
    int mreg[8]; unsigned ureg[8];
#pragma unroll
    for (int g = 0; g < 8; ++g) {
      const int i = g * 64 + lane;
      int m = mx[i];
      float um = umx[i];
      unsigned bit = 1u << (m & 31);
      bool dirty = ((bmDup[m >> 5] | bmCand[m >> 5]) & bit) != 0;
      float mean = (float)((sum0 + (double)i) * (1.0 / 65536.0));
      bool dec = um < mean;
      mreg[g] = m | (dirty ? 0x10000 : 0) | (dec ? 0x20000 : 0);
      ureg[g] = __float_as_uint(um);
    }
    int ptr = 0;
    int c0 = si[0], c1 = si[1], c2 = si[2], c3 = si[3];

#define SCAN_STEP(G, J)                                                       \
  {                                                                           \
    const int I = (G) * 64 + (J);                                             \
    const int RM = __builtin_amdgcn_readlane(mreg[G], (J));                   \
    const int mxi = RM & 0xFFFF;                                              \
    const int fl = (RM >> 16) & 3;                                            \
    int sel, chain; bool adv;                                                 \
    if (!(fl & 1)) {                                                          \
      if (fl & 2) { sel = mxi; chain = 0; adv = false; }                      \
      else { sel = c0 & 0xFFFF; chain = 0; adv = true; }                      \
    } else {                                                                  \
      const float RU = __uint_as_float(__builtin_amdgcn_readlane(ureg[G], (J))); \
      const int cc = (int)cnt8[mxi];                                          \
      const float mean = (float)((sum0 + (double)I) * (1.0 / 65536.0));       \
      const float uu = RU + (float)cc;                                        \
      const int cand_i = c0 & 0xFFFF;                                         \
      if (uu < mean) { sel = mxi; chain = cc; adv = (mxi == cand_i); }        \
      else { sel = cand_i; chain = 0; adv = true; }                           \
    }                                                                         \
    if (lane == 0) {                                                          \
      cnt8[sel] = (unsigned char)(chain + 1);                                 \
      idxl[I] = sel;                                                          \
      chl[I] = chain;                                                         \
    }                                                                         \
    if (adv) {                                                                \
      for (;;) {                                                              \
        ++ptr;                                                                \
        if (ptr >= nc) {                                                      \
          ptr = nc - 1;                                                       \
          c0 = si[ptr];                                                       \
          c1 = si[ptr + 1 < 2048 ? ptr + 1 : 2047];                           \
          c2 = si[ptr + 2 < 2048 ? ptr + 2 : 2047];                           \
          c3 = si[ptr + 3 < 2048 ? ptr + 3 : 2047];                           \
          break;                                                              \
        }                                                                     \
        c0 = c1; c1 = c2; c2 = c3;                                            \
        c3 = si[ptr + 3 < 2048 ? ptr + 3 : 2047];                             \
        if (!(c0 & (1 << 30))) break;                                         \
        if (cnt8[c0 & 0xFFFF] == 0) break;                                    \
      }                                                                       \
    }                                                                         \
  }

#pragma unroll
    for (int g = 0; g < 8; ++g) {
      for (int j = 0; j < 64; j += 4) {
        SCAN_STEP(g, j + 0);
        SCAN_STEP(g, j + 1);
        SCAN_STEP(g, j + 2);
        SCAN_STEP(g, j + 3);
      }
    }
#undef SCAN_STEP
  }
  __syncthreads();
  if (t < 512) {
    idxA[t] = idxl[t];
    chainA[t] = chl[t];
  }
  for (int p = t; p < 65536; p += 1024) {
    int c = (int)cnt8[p];
    if (c > 0) new_usage[p] = usage[p] + (float)c;
  }
}

// ============ parallel gate for first-occurrence steps ============
__global__ void k_gate0(const int* __restrict__ idxA, const int* __restrict__ chainA,
                        const float* __restrict__ memory, const float* __restrict__ query,
                        const float* __restrict__ Gq, const float* __restrict__ Gr,
                        const float* __restrict__ Wg, float* __restrict__ new_memory) {
  const int i = blockIdx.x;
  if (chainA[i] != 0) return;
  const int sel = idxA[i];
  __shared__ __align__(16) float oldr[256];
  const int d = threadIdx.x;
  oldr[d] = memory[(size_t)sel * 256 + d];
  __syncthreads();
  const float4* wg = reinterpret_cast<const float4*>(Wg + (size_t)d * 768 + 256);
  float acc = Gq[(size_t)i * 256 + d] + Gr[(size_t)i * 256 + d];
#pragma unroll 8
  for (int j4 = 0; j4 < 64; ++j4) {
    float4 w = wg[j4];
    float4 o = *reinterpret_cast<const float4*>(&oldr[j4 * 4]);
    acc += w.x * o.x + w.y * o.y + w.z * o.z + w.w * o.w;
  }
  float g = 1.0f / (1.0f + __expf(-acc));
  new_memory[(size_t)sel * 256 + d] = g * query[(size_t)i * 256 + d] + (1.0f - g) * oldr[d];
}

// ============ chained steps: one block per chained slot, serial within slot ============
__global__ void k_chain(const int* __restrict__ idxA, const int* __restrict__ chainA,
                        const float* __restrict__ query, const float* __restrict__ Gq,
                        const float* __restrict__ Gr, const float* __restrict__ Wg,
                        float* __restrict__ new_memory) {
  __shared__ int flags[512];
  __shared__ int idxs[512];
  __shared__ __align__(16) float oldr[256];
  const int j0 = blockIdx.x;
  const int d = threadIdx.x;
  flags[d] = chainA[d]; flags[d + 256] = chainA[d + 256];
  idxs[d] = idxA[d]; idxs[d + 256] = idxA[d + 256];
  __syncthreads();
  if (flags[j0] != 1) return;
  const int slot = idxs[j0];
  for (int i = j0; i < 512; ++i) {
    if (idxs[i] != slot) continue;
    oldr[d] = new_memory[(size_t)slot * 256 + d];
    __syncthreads();
    const float4* wg = reinterpret_cast<const float4*>(Wg + (size_t)d * 768 + 256);
    float acc = Gq[(size_t)i * 256 + d] + Gr[(size_t)i * 256 + d];
#pragma unroll 8
    for (int j4 = 0; j4 < 64; ++j4) {
      float4 w = wg[j4];
      float4 o = *reinterpret_cast<const float4*>(&oldr[j4 * 4]);
      acc += w.x * o.x + w.y * o.y + w.z * o.z + w.w * o.w;
    }
    float g = 1.0f / (1.0f + __expf(-acc));
    new_memory[(size_t)slot * 256 + d] = g * query[(size_t)i * 256 + d] + (1.0f - g) * oldr[d];
    __threadfence();
    __syncthreads();
  }
}

extern "C" void kernel_launch(void* const* d_in, const int* in_sizes, int n_in,
                              void* d_out, int out_size, void* d_ws, size_t ws_size,
                              hipStream_t stream) {
  const float* query  = (const float*)d_in[0];
  const float* memory = (const float*)d_in[1];
  const float* Wq = (const float*)d_in[2];
  const float* bq = (const float*)d_in[3];
  const float* Wk = (const float*)d_in[4];
  const float* bk = (const float*)d_in[5];
  const float* Wv = (const float*)d_in[6];
  const float* bv = (const float*)d_in[7];
  const float* Wo = (const float*)d_in[8];
  const float* bo = (const float*)d_in[9];
  const float* Wg = (const float*)d_in[10];
  const float* bg = (const float*)d_in[11];
  const float* usage = (const float*)d_in[12];

  float* out = (float*)d_out;
  float* retr_out = out;
  float* newmem = out + 131072;
  float* newusage = out + 131072 + 16777216;
  float* part2 = newmem;                                      // [64][512][256] f32 (32 MB)
  unsigned short* VT = (unsigned short*)(newmem + 8388608);   // [256][65536] bf16 (32 MB)

  float* ws = (float*)d_ws;
  float* Qb    = ws + OFF_Q;
  float* Gqb   = ws + OFF_GQ;
  float* Grb   = ws + OFF_GR;
  float* Rpreb = ws + OFF_RPRE;
  unsigned short* QBF   = (unsigned short*)(ws + OFF_QBF);
  unsigned short* WKBF  = (unsigned short*)(ws + OFF_WKBF);
  unsigned short* WVBF  = (unsigned short*)(ws + OFF_WVBF);
  unsigned short* KB    = (unsigned short*)(ws + OFF_KB);
  float* ZPb   = ws + OFF_ZP;
  float* AMVb  = ws + OFF_AMV;
  int*   AMIb  = (int*)(ws + OFF_AMI);
  int*   MXb   = (int*)(ws + OFF_MX);
  float* UMXb  = ws + OFF_UMX;
  float* CANDVb = ws + OFF_CANDV;
  int*   CANDIb = (int*)(ws + OFF_CANDI);
  float* BSUMb  = ws + OFF_BSUM;
  int*   CNTb   = (int*)(ws + OFF_CNT);
  int*   IDXAb  = (int*)(ws + OFF_IDXA);
  int*   CHAINb = (int*)(ws + OFF_CHAIN);

  hipMemsetAsync(CNTb, 0, sizeof(int), stream);

  k_cvt<<<32, 256, 0, stream>>>(Wk, WKBF, 65536);
  k_cvt<<<32, 256, 0, stream>>>(Wv, WVBF, 65536);
  // projmm (0..1023) || qgq (1024..1535)
  k_projq<<<1536, 256, 0, stream>>>(memory, WKBF, bk, WVBF, bv, KB, VT,
                                    query, Wq, bq, Wg, bg, Qb, Gqb, QBF);
  k_fused<<<dim3(64, 8), 256, 0, stream>>>(QBF, KB, VT, part2, ZPb, AMVb, AMIb);
  // amax2 (0..511) || cand (512..767) || rcomb+Z (768..1279)
  k_par0<<<1280, 256, 0, stream>>>(Qb, Wk, bk, memory, ZPb, AMVb, AMIb, usage,
                                   MXb, UMXb, CANDVb, CANDIb, CNTb, BSUMb,
                                   part2, Rpreb);

  hipMemcpyAsync(newusage, usage, (size_t)65536 * 4, hipMemcpyDeviceToDevice, stream);

  // scan (0) || out1 (1..128) || full newmem copy (129..1152)
  k_par1<<<1153, 1024, 0, stream>>>(CANDVb, CANDIb, CNTb, BSUMb, MXb, UMXb, usage,
                                    IDXAb, CHAINb, newusage, Rpreb, Wo, bo, Wg,
                                    retr_out, Grb, memory, newmem);

  k_gate0<<<512, 256, 0, stream>>>(IDXAb, CHAINb, memory, query, Gqb, Grb, Wg, newmem);
  k_chain<<<512, 256, 0, stream>>>(IDXAb, CHAINb, query, Gqb, Grb, Wg, newmem);
}

// Round 15
// 401.699 us; speedup vs baseline: 1.2398x; 1.2398x over previous
//
#include <hip/hip_runtime.h>
#include <hip/hip_bf16.h>
#include <math.h>

// ---- workspace layout (float offsets) ----
static const size_t OFF_Q     = 0;          // [512][256] f32
static const size_t OFF_GQ    = 131072;     // [512][256] f32
static const size_t OFF_GR    = 262144;     // [512][256] f32
static const size_t OFF_RPRE  = 393216;     // [512][256] f32
static const size_t OFF_QBF   = 524288;     // [512][256] bf16 (65536 f32 slots)
static const size_t OFF_WKBF  = 8978432;    // [256][256] bf16 (32768 slots)
static const size_t OFF_WVBF  = 9011200;    // [256][256] bf16 (32768 slots)
static const size_t OFF_KB    = 9043968;    // [65536][256] bf16 (8388608 slots)
static const size_t OFF_ZP    = 17432576;   // [4][512][64] f32 (Z partials)
static const size_t OFF_AMV   = 17698816;   // [64][512][2] f32
static const size_t OFF_AMI   = 17764352;   // [64][512][2] i32
static const size_t OFF_MX    = 17829888;   // [512] i32
static const size_t OFF_UMX   = 17830400;   // [512] f32
static const size_t OFF_CANDV = 17830912;   // [2048] f32
static const size_t OFF_CANDI = 17835008;   // [2048] i32
static const size_t OFF_BSUM  = 17839104;   // [256] f32
static const size_t OFF_CNT   = 17839360;   // [16] i32
static const size_t OFF_IDXA  = 17839376;   // [512] i32
static const size_t OFF_CHAIN = 17839888;   // [512] i32

typedef short v8s __attribute__((ext_vector_type(8)));
typedef float f32x4 __attribute__((ext_vector_type(4)));

__device__ __forceinline__ unsigned short f2bf(float f) {
  unsigned int x = __float_as_uint(f);
  unsigned int r = (x + 0x7fffu + ((x >> 16) & 1u)) >> 16;
  return (unsigned short)r;
}

// async global->LDS DMA, 16 B per lane; LDS dest = wave-uniform base + lane*16
__device__ __forceinline__ void gld16(const void* g, void* l) {
  __builtin_amdgcn_global_load_lds(
      (const __attribute__((address_space(1))) void*)g,
      (__attribute__((address_space(3))) void*)l, 16, 0, 0);
}

// ============ cvt: fp32 -> bf16 (8 elems/thread) — weights only ============
__global__ void k_cvt(const float* __restrict__ in, unsigned short* __restrict__ out, int n) {
  int i = (blockIdx.x * 256 + threadIdx.x) * 8;
  if (i + 8 <= n) {
    float4 a = *reinterpret_cast<const float4*>(in + i);
    float4 b = *reinterpret_cast<const float4*>(in + i + 4);
    ushort4 o1 = {f2bf(a.x), f2bf(a.y), f2bf(a.z), f2bf(a.w)};
    ushort4 o2 = {f2bf(b.x), f2bf(b.y), f2bf(b.z), f2bf(b.w)};
    *reinterpret_cast<ushort4*>(out + i) = o1;
    *reinterpret_cast<ushort4*>(out + i + 4) = o2;
  }
}

// ============ PROJQ: blocks 0..1023 = MFMA K/V projection; 1024..1535 = Q/Gq GEMVs ============
__global__ __launch_bounds__(256) void k_projq(const float* __restrict__ mem,
    const unsigned short* __restrict__ Wkbf, const float* __restrict__ bk,
    const unsigned short* __restrict__ Wvbf, const float* __restrict__ bv,
    unsigned short* __restrict__ Kout, unsigned short* __restrict__ Vt,
    const float* __restrict__ query, const float* __restrict__ Wq,
    const float* __restrict__ bq, const float* __restrict__ Wg,
    const float* __restrict__ bg, float* __restrict__ Q,
    float* __restrict__ Gq, unsigned short* __restrict__ Qbf) {
  __shared__ __align__(16) char sbuf[36864];
  const int bid = blockIdx.x;
  const int t = threadIdx.x;

  if (bid >= 1024) {
    // ---- qgq: Q = query@Wq.T + bq (f32 + bf16*0.125) ; Gq = query@Wg[:,0:256].T + bg ----
    float* qrow = reinterpret_cast<float*>(sbuf);
    const int i = bid - 1024;
    const int d = t;
    qrow[d] = query[(size_t)i * 256 + d];
    __syncthreads();
    const float4* wq = reinterpret_cast<const float4*>(Wq + (size_t)d * 256);
    float acc = 0.f;
#pragma unroll 8
    for (int j4 = 0; j4 < 64; ++j4) {
      float4 w = wq[j4];
      float4 q = *reinterpret_cast<const float4*>(&qrow[j4 * 4]);
      acc += w.x * q.x + w.y * q.y + w.z * q.z + w.w * q.w;
    }
    float qv = acc + bq[d];
    Q[(size_t)i * 256 + d] = qv;
    Qbf[(size_t)i * 256 + d] = f2bf(qv * 0.125f);
    const float4* wg = reinterpret_cast<const float4*>(Wg + (size_t)d * 768);
    float acc2 = 0.f;
#pragma unroll 8
    for (int j4 = 0; j4 < 64; ++j4) {
      float4 w = wg[j4];
      float4 q = *reinterpret_cast<const float4*>(&qrow[j4 * 4]);
      acc2 += w.x * q.x + w.y * q.y + w.z * q.z + w.w * q.w;
    }
    Gq[(size_t)i * 256 + d] = acc2 + bg[d];
    return;
  }

  // ---- projmm ----
  const int w = t >> 6, l = t & 63, l15 = l & 15, lg = l >> 4;
  const int mb = bid * 64;
  const int mrow = mb + w * 16 + l15;
  v8s am[8];
#pragma unroll
  for (int kk = 0; kk < 8; ++kk) {
    const float* src = mem + (size_t)mrow * 256 + kk * 32 + lg * 8;
    float4 f0 = *reinterpret_cast<const float4*>(src);
    float4 f1 = *reinterpret_cast<const float4*>(src + 4);
    v8s a;
    a[0] = (short)f2bf(f0.x); a[1] = (short)f2bf(f0.y);
    a[2] = (short)f2bf(f0.z); a[3] = (short)f2bf(f0.w);
    a[4] = (short)f2bf(f1.x); a[5] = (short)f2bf(f1.y);
    a[6] = (short)f2bf(f1.z); a[7] = (short)f2bf(f1.w);
    am[kk] = a;
  }

#define STAGE_W(Wsrc, dt)                                                     \
  {                                                                           \
    _Pragma("unroll")                                                         \
    for (int j = 0; j < 8; ++j) {                                             \
      int off = j * 4096 + w * 1024 + l * 16;                                 \
      int row = off >> 9;                                                     \
      int col = off & 511;                                                    \
      gld16(reinterpret_cast<const char*>(Wsrc) +                             \
                (size_t)((dt) * 64 + row) * 512 + (col ^ ((row & 7) << 4)),   \
            sbuf + j * 4096 + w * 1024);                                      \
    }                                                                         \
  }

  // ---- K = mem @ Wk^T + bk ----
  {
    f32x4 acc[16];
#pragma unroll
    for (int df = 0; df < 16; ++df) {
      float bz = bk[df * 16 + l15];
      acc[df] = (f32x4){bz, bz, bz, bz};
    }
    for (int dt = 0; dt < 4; ++dt) {
      STAGE_W(Wkbf, dt);
      asm volatile("s_waitcnt vmcnt(0)" ::: "memory");
      __builtin_amdgcn_s_barrier();
#pragma unroll
      for (int kk = 0; kk < 8; ++kk)
#pragma unroll
        for (int dfl = 0; dfl < 4; ++dfl) {
          const int row = dfl * 16 + l15;
          const v8s b = *reinterpret_cast<const v8s*>(
              sbuf + row * 512 + ((kk * 64 + lg * 16) ^ ((row & 7) << 4)));
          acc[dt * 4 + dfl] =
              __builtin_amdgcn_mfma_f32_16x16x32_bf16(am[kk], b, acc[dt * 4 + dfl], 0, 0, 0);
        }
      asm volatile("" ::: "memory");
      __builtin_amdgcn_s_barrier();
    }
    unsigned short* bounce = reinterpret_cast<unsigned short*>(sbuf);
#pragma unroll
    for (int df = 0; df < 16; ++df)
#pragma unroll
      for (int r = 0; r < 4; ++r)
        bounce[(w * 16 + lg * 4 + r) * 264 + df * 16 + l15] = f2bf(acc[df][r]);
  }
  __syncthreads();
  {
    unsigned short* bounce = reinterpret_cast<unsigned short*>(sbuf);
    int row = t >> 2, quad = t & 3;
    const uint4* src = reinterpret_cast<const uint4*>(&bounce[row * 264 + quad * 64]);
    uint4* dst = reinterpret_cast<uint4*>(Kout + (size_t)(mb + row) * 256 + quad * 64);
#pragma unroll
    for (int x = 0; x < 8; ++x) dst[x] = src[x];
  }
  __syncthreads();
  // ---- V = mem @ Wv^T + bv, stored transposed Vt[d][m] ----
  {
    f32x4 acc[16];
#pragma unroll
    for (int df = 0; df < 16; ++df) {
      float bz = bv[df * 16 + l15];
      acc[df] = (f32x4){bz, bz, bz, bz};
    }
    for (int dt = 0; dt < 4; ++dt) {
      STAGE_W(Wvbf, dt);
      asm volatile("s_waitcnt vmcnt(0)" ::: "memory");
      __builtin_amdgcn_s_barrier();
#pragma unroll
      for (int kk = 0; kk < 8; ++kk)
#pragma unroll
        for (int dfl = 0; dfl < 4; ++dfl) {
          const int row = dfl * 16 + l15;
          const v8s b = *reinterpret_cast<const v8s*>(
              sbuf + row * 512 + ((kk * 64 + lg * 16) ^ ((row & 7) << 4)));
          acc[dt * 4 + dfl] =
              __builtin_amdgcn_mfma_f32_16x16x32_bf16(am[kk], b, acc[dt * 4 + dfl], 0, 0, 0);
        }
      asm volatile("" ::: "memory");
      __builtin_amdgcn_s_barrier();
    }
    unsigned short* bounce = reinterpret_cast<unsigned short*>(sbuf);
#pragma unroll
    for (int df = 0; df < 16; ++df)
#pragma unroll
      for (int r = 0; r < 4; ++r)
        bounce[(df * 16 + l15) * 72 + w * 16 + lg * 4 + r] = f2bf(acc[df][r]);
  }
  __syncthreads();
  {
    const unsigned short* bounce = reinterpret_cast<const unsigned short*>(sbuf);
    const uint4* src = reinterpret_cast<const uint4*>(&bounce[t * 72]);
    uint4* dst = reinterpret_cast<uint4*>(Vt + (size_t)t * 65536 + mb);
#pragma unroll
    for (int x = 0; x < 8; ++x) dst[x] = src[x];
  }
#undef STAGE_W
}

// ============ FUSED pass: scores + no-max exp + Z accumulation + PV + top-2 ============
__global__ __launch_bounds__(256, 2) void k_fused(const unsigned short* __restrict__ Qbf,
    const unsigned short* __restrict__ Kb, const unsigned short* __restrict__ Vt,
    float* __restrict__ part2, float* __restrict__ zpart,
    float* __restrict__ amv, int* __restrict__ ami) {
  __shared__ __align__(16) unsigned short KsBuf[2][8192];
  __shared__ __align__(16) unsigned short VsBuf[2][8192];
  __shared__ __align__(16) unsigned short Pl[4][16][40];
  const int mc = blockIdx.x;   // 0..63
  const int qc = blockIdx.y;   // 0..7
  const int t = threadIdx.x;
  const int w = t >> 6, l = t & 63, l15 = l & 15, lg = l >> 4;
  const int qbase = qc * 64 + w * 16;
  const char* Kbc = reinterpret_cast<const char*>(Kb);
  const char* Vtc = reinterpret_cast<const char*>(Vt);
  char* lds_k = reinterpret_cast<char*>(KsBuf);
  char* lds_v = reinterpret_cast<char*>(VsBuf);
  v8s aq[4][2];
#pragma unroll
  for (int h = 0; h < 4; ++h)
#pragma unroll
    for (int kk = 0; kk < 2; ++kk)
      aq[h][kk] = *reinterpret_cast<const v8s*>(
          Qbf + (size_t)(qbase + l15) * 256 + h * 64 + kk * 32 + lg * 8);
  f32x4 racc[4][4] = {};
  float zs[4][4] = {};
  float v1[4], v2[4]; int i1[4], i2[4];
#pragma unroll
  for (int r = 0; r < 4; ++r) { v1[r] = -INFINITY; v2[r] = -INFINITY; i1[r] = 0x7fffffff; i2[r] = 0x7fffffff; }
  const int mbase = mc * 1024;

#define STAGE_K2(bufsel, m0)                                                  \
  {                                                                           \
    _Pragma("unroll")                                                         \
    for (int j = 0; j < 4; ++j) {                                             \
      int off = w * 4096 + j * 1024 + l * 16;                                 \
      int row = off >> 9;                                                     \
      int col = off & 511;                                                    \
      gld16(Kbc + (size_t)((m0) + row) * 512 + (col ^ ((row & 7) << 4)),      \
            lds_k + (bufsel) * 16384 + w * 4096 + j * 1024);                  \
    }                                                                         \
  }
#define STAGE_V2(bufsel, m0)                                                  \
  {                                                                           \
    _Pragma("unroll")                                                         \
    for (int j = 0; j < 4; ++j) {                                             \
      int off = w * 4096 + j * 1024 + l * 16;                                 \
      int row = off >> 6;                                                     \
      int col = off & 63;                                                     \
      gld16(Vtc + (size_t)row * 131072 + (size_t)(m0) * 2 +                   \
                (col ^ (((row >> 1) & 3) << 4)),                              \
            lds_v + (bufsel) * 16384 + w * 4096 + j * 1024);                  \
    }                                                                         \
  }

  STAGE_K2(0, mbase);
  STAGE_V2(0, mbase);
  for (int mt = 0; mt < 32; ++mt) {
    const int m0 = mbase + mt * 32;
    if (mt < 31) {
      STAGE_K2((mt + 1) & 1, m0 + 32);
      STAGE_V2((mt + 1) & 1, m0 + 32);
      asm volatile("s_waitcnt vmcnt(8)" ::: "memory");
    } else {
      asm volatile("s_waitcnt vmcnt(0)" ::: "memory");
    }
    __builtin_amdgcn_s_barrier();
    const char* kbp = lds_k + (mt & 1) * 16384;
    const char* vbp = lds_v + (mt & 1) * 16384;
    float cacc[4][2] = {};
#pragma unroll
    for (int h = 0; h < 4; ++h) {
      f32x4 sacc[2] = {};
#pragma unroll
      for (int nf = 0; nf < 2; ++nf) {
        const int row = nf * 16 + l15;
        const int sw = (row & 7) << 4;
#pragma unroll
        for (int kk = 0; kk < 2; ++kk) {
          const v8s b = *reinterpret_cast<const v8s*>(
              kbp + row * 512 + ((h * 128 + kk * 64 + lg * 16) ^ sw));
          sacc[nf] = __builtin_amdgcn_mfma_f32_16x16x32_bf16(aq[h][kk], b, sacc[nf], 0, 0, 0);
        }
      }
#pragma unroll
      for (int nf = 0; nf < 2; ++nf)
#pragma unroll
        for (int r = 0; r < 4; ++r) {
          float e = __expf(sacc[nf][r]);     // scores pre-scaled by 0.125 via Qbf
          cacc[r][nf] += e;
          zs[r][h] += e;
          Pl[w][lg * 4 + r][nf * 16 + l15] =
              (unsigned short)(__float_as_uint(e) >> 16);
        }
      const v8s pa = *reinterpret_cast<const v8s*>(
          reinterpret_cast<const char*>(&Pl[w][l15][0]) + lg * 16);
#pragma unroll
      for (int df = 0; df < 4; ++df) {
        const int vrow = h * 64 + df * 16 + l15;
        const v8s vb = *reinterpret_cast<const v8s*>(
            vbp + vrow * 64 + ((lg * 16) ^ (((vrow >> 1) & 3) << 4)));
        racc[h][df] = __builtin_amdgcn_mfma_f32_16x16x32_bf16(pa, vb, racc[h][df], 0, 0, 0);
      }
    }
#pragma unroll
    for (int r = 0; r < 4; ++r)
#pragma unroll
      for (int nf = 0; nf < 2; ++nf) {
        float val = cacc[r][nf];
        int idx = m0 + nf * 16 + l15;
        if (val > v1[r] || (val == v1[r] && idx < i1[r])) {
          v2[r] = v1[r]; i2[r] = i1[r]; v1[r] = val; i1[r] = idx;
        } else if (val > v2[r] || (val == v2[r] && idx < i2[r])) {
          v2[r] = val; i2[r] = idx;
        }
      }
    asm volatile("" ::: "memory");
    __builtin_amdgcn_s_barrier();
  }
#undef STAGE_K2
#undef STAGE_V2
#pragma unroll
  for (int h = 0; h < 4; ++h)
#pragma unroll
    for (int df = 0; df < 4; ++df)
#pragma unroll
      for (int r = 0; r < 4; ++r) {
        int q = qbase + lg * 4 + r;
        part2[(size_t)mc * 131072 + (size_t)q * 256 + h * 64 + df * 16 + l15] = racc[h][df][r];
      }
#pragma unroll
  for (int mask = 1; mask <= 8; mask <<= 1)
#pragma unroll
    for (int r = 0; r < 4; ++r)
#pragma unroll
      for (int h = 0; h < 4; ++h)
        zs[r][h] += __shfl_xor(zs[r][h], mask);
  if (l15 == 0) {
#pragma unroll
    for (int r = 0; r < 4; ++r)
#pragma unroll
      for (int h = 0; h < 4; ++h) {
        int q = qbase + lg * 4 + r;
        zpart[((size_t)h * 512 + q) * 64 + mc] = zs[r][h];
      }
  }
#pragma unroll
  for (int mask = 1; mask <= 8; mask <<= 1) {
#pragma unroll
    for (int r = 0; r < 4; ++r) {
      float ov1 = __shfl_xor(v1[r], mask); int oi1 = __shfl_xor(i1[r], mask);
      float ov2 = __shfl_xor(v2[r], mask); int oi2 = __shfl_xor(i2[r], mask);
      bool cGTa = ov1 > v1[r] || (ov1 == v1[r] && oi1 < i1[r]);
      float nv1, nv2; int ni1, ni2;
      if (cGTa) {
        nv1 = ov1; ni1 = oi1;
        bool aGTd = v1[r] > ov2 || (v1[r] == ov2 && i1[r] < oi2);
        nv2 = aGTd ? v1[r] : ov2; ni2 = aGTd ? i1[r] : oi2;
      } else {
        nv1 = v1[r]; ni1 = i1[r];
        bool bGTc = v2[r] > ov1 || (v2[r] == ov1 && i2[r] < oi1);
        nv2 = bGTc ? v2[r] : ov1; ni2 = bGTc ? i2[r] : oi1;
      }
      v1[r] = nv1; i1[r] = ni1; v2[r] = nv2; i2[r] = ni2;
    }
  }
  if (l15 == 0) {
#pragma unroll
    for (int r = 0; r < 4; ++r) {
      int q = qbase + lg * 4 + r;
      amv[((size_t)mc * 512 + q) * 2] = v1[r];
      amv[((size_t)mc * 512 + q) * 2 + 1] = v2[r];
      ami[((size_t)mc * 512 + q) * 2] = i1[r];
      ami[((size_t)mc * 512 + q) * 2 + 1] = i2[r];
    }
  }
}

// ============ PAR0: amax2 (0..511) | cand (512..767) | rcomb+Z (768..1279) ============
__global__ __launch_bounds__(256) void k_par0(const float* __restrict__ Qf,
    const float* __restrict__ Wk, const float* __restrict__ bk,
    const float* __restrict__ memory, const float* __restrict__ zpart,
    const float* __restrict__ amv, const int* __restrict__ ami,
    const float* __restrict__ usage, int* __restrict__ mx, float* __restrict__ umx,
    float* __restrict__ candv, int* __restrict__ candi, int* __restrict__ cnt,
    float* __restrict__ bsum, const float* __restrict__ part2,
    float* __restrict__ rpre) {
  __shared__ float u[4][256];
  __shared__ float ch[4];
  __shared__ float qrow[256];
  __shared__ float redv[4];
  __shared__ int redi[4];
  __shared__ float zish[4];
  const int bid = blockIdx.x;
  const int t = threadIdx.x;

  if (bid >= 768) {
    // ---- rcomb with inline Z ----
    const int b = bid - 768;
    const int h = t >> 6, c = t & 63;
    float z = zpart[((size_t)h * 512 + b) * 64 + c];
#pragma unroll
    for (int mask = 32; mask >= 1; mask >>= 1) z += __shfl_xor(z, mask);
    const float iZ = 1.0f / z;
    const int d = t;
    float s = 0.f;
    for (int cc = 0; cc < 64; ++cc) s += part2[(size_t)cc * 131072 + (size_t)b * 256 + d];
    rpre[(size_t)b * 256 + d] = s * iZ;
    return;
  }
  if (bid >= 512) {
    // ---- cand ----
    float* sred = qrow;
    int g = (bid - 512) * 256 + t;
    float uu = usage[g];
    sred[t] = uu;
    __syncthreads();
    for (int s = 128; s > 0; s >>= 1) {
      if (t < s) sred[t] += sred[t + s];
      __syncthreads();
    }
    if (t == 0) bsum[bid - 512] = sred[0];
    if (uu < 0.25f) {
      int pos = atomicAdd(cnt, 1);
      if (pos < 2048) { candv[pos] = uu; candi[pos] = g; }
    }
    return;
  }

  // ---- amax2 with inline Z ----
  const int row = bid;
  {
    const int h = t >> 6, c = t & 63;
    float z = zpart[((size_t)h * 512 + row) * 64 + c];
#pragma unroll
    for (int mask = 32; mask >= 1; mask >>= 1) z += __shfl_xor(z, mask);
    if (c == 0) zish[h] = 1.0f / z;
  }
  qrow[t] = Qf[(size_t)row * 256 + t];
  __syncthreads();
#pragma unroll
  for (int h = 0; h < 4; ++h) {
    float s = 0.f;
    for (int d = 0; d < 64; ++d) s += qrow[h * 64 + d] * Wk[(size_t)(h * 64 + d) * 256 + t];
    u[h][t] = s;
  }
  if (t < 4) {
    float s = 0.f;
    for (int d = 0; d < 64; ++d) s += qrow[t * 64 + d] * bk[t * 64 + d];
    ch[t] = s;
  }
  __syncthreads();
  const int wv = t >> 6, ln = t & 63;
  const float Zi0 = zish[0], Zi1 = zish[1], Zi2 = zish[2], Zi3 = zish[3];
  float bestv = -INFINITY; int besti = 0x7fffffff;
  for (int c = wv; c < 128; c += 4) {
    int m = ami[((size_t)(c >> 1) * 512 + row) * 2 + (c & 1)];
    float s0 = 0.f, s1 = 0.f, s2 = 0.f, s3 = 0.f;
#pragma unroll
    for (int k = 0; k < 4; ++k) {
      float mv = memory[(size_t)m * 256 + ln + 64 * k];
      s0 += mv * u[0][ln + 64 * k];
      s1 += mv * u[1][ln + 64 * k];
      s2 += mv * u[2][ln + 64 * k];
      s3 += mv * u[3][ln + 64 * k];
    }
#pragma unroll
    for (int mask = 32; mask >= 1; mask >>= 1) {
      s0 += __shfl_xor(s0, mask); s1 += __shfl_xor(s1, mask);
      s2 += __shfl_xor(s2, mask); s3 += __shfl_xor(s3, mask);
    }
    float a = __expf((s0 + ch[0]) * 0.125f) * Zi0 +
              __expf((s1 + ch[1]) * 0.125f) * Zi1 +
              __expf((s2 + ch[2]) * 0.125f) * Zi2 +
              __expf((s3 + ch[3]) * 0.125f) * Zi3;
    if (a > bestv || (a == bestv && m < besti)) { bestv = a; besti = m; }
  }
  if (ln == 0) { redv[wv] = bestv; redi[wv] = besti; }
  __syncthreads();
  if (t == 0) {
    float bv = -INFINITY; int bi = 0x7fffffff;
#pragma unroll
    for (int q = 0; q < 4; ++q) {
      if (redv[q] > bv || (redv[q] == bv && redi[q] < bi)) { bv = redv[q]; bi = redi[q]; }
    }
    mx[row] = bi;
    umx[row] = usage[bi];
  }
}

// ============ PAR1: scan (0) | out1 x4 rows (1..128) | full newmem copy (129..1152) ============
__global__ __launch_bounds__(1024) void k_par1(const float* __restrict__ candv_g,
    const int* __restrict__ candi_g, const int* __restrict__ cnt_g,
    const float* __restrict__ bsum, const int* __restrict__ mx,
    const float* __restrict__ umx, const float* __restrict__ usage,
    int* __restrict__ idxA, int* __restrict__ chainA, float* __restrict__ new_usage,
    const float* __restrict__ rpre, const float* __restrict__ Wo,
    const float* __restrict__ bo, const float* __restrict__ Wg,
    float* __restrict__ retr, float* __restrict__ Gr,
    const float* __restrict__ memory, float* __restrict__ newmem) {
  __shared__ float bV[256 * 24];
  __shared__ int   bI[256 * 24];
  __shared__ unsigned char cnt8[65536];
  __shared__ int si[2048];
  __shared__ unsigned int bmSeen[2048];
  __shared__ unsigned int bmDup[2048];
  __shared__ unsigned int bmCand[2048];
  __shared__ int idxl[512];
  __shared__ int chl[512];
  __shared__ int bcnt[256];
  __shared__ int bpre[256];
  __shared__ double dred[256];
  __shared__ int totsh;

  const int bid = blockIdx.x;
  const int t = threadIdx.x;

  if (bid >= 129) {
    const size_t base = (size_t)(bid - 129) * 16384 + (size_t)t * 16;
#pragma unroll
    for (int j = 0; j < 4; ++j) {
      size_t idx = base + (size_t)j * 4;
      *reinterpret_cast<float4*>(newmem + idx) =
          *reinterpret_cast<const float4*>(memory + idx);
    }
    return;
  }
  if (bid >= 1) {
    float* rr = bV;
    float* rf = bV + 1024;
    const int r4 = t >> 8, d = t & 255;
    const int i = (bid - 1) * 4 + r4;
    rr[r4 * 256 + d] = rpre[(size_t)i * 256 + d];
    __syncthreads();
    const float4* wo = reinterpret_cast<const float4*>(Wo + (size_t)d * 256);
    float acc = 0.f;
#pragma unroll 8
    for (int j4 = 0; j4 < 64; ++j4) {
      float4 w = wo[j4];
      float4 q = *reinterpret_cast<const float4*>(&rr[r4 * 256 + j4 * 4]);
      acc += w.x * q.x + w.y * q.y + w.z * q.z + w.w * q.w;
    }
    float v = acc + bo[d];
    retr[(size_t)i * 256 + d] = v;
    rf[r4 * 256 + d] = v;
    __syncthreads();
    const float4* wg = reinterpret_cast<const float4*>(Wg + (size_t)d * 768 + 512);
    float acc2 = 0.f;
#pragma unroll 8
    for (int j4 = 0; j4 < 64; ++j4) {
      float4 w = wg[j4];
      float4 q = *reinterpret_cast<const float4*>(&rf[r4 * 256 + j4 * 4]);
      acc2 += w.x * q.x + w.y * q.y + w.z * q.z + w.w * q.w;
    }
    Gr[(size_t)i * 256 + d] = acc2;
    return;
  }

  // ---- block 0: selection scan (v4) ----
  const int ncg0 = cnt_g[0];
  const int ncg = ncg0 > 2048 ? 2048 : ncg0;

  for (int p = t; p < 2048; p += 1024) {
    si[p] = 0; bmSeen[p] = 0u; bmDup[p] = 0u; bmCand[p] = 0u;
  }
  {
    uint4 z; z.x = 0u; z.y = 0u; z.z = 0u; z.w = 0u;
    uint4* c4 = reinterpret_cast<uint4*>(cnt8);
#pragma unroll
    for (int r = 0; r < 4; ++r) c4[t + r * 1024] = z;
  }
  if (t < 256) { bcnt[t] = 0; dred[t] = (double)bsum[t]; }
  __syncthreads();
  for (int s = 128; s > 0; s >>= 1) {
    if (t < s) dred[t] += dred[t + s];
    __syncthreads();
  }
  if (t < 512) {
    int m = mx[t];
    unsigned bit = 1u << (m & 31);
    unsigned old = atomicOr(&bmSeen[m >> 5], bit);
    if (old & bit) atomicOr(&bmDup[m >> 5], bit);
  }
  for (int p = t; p < ncg; p += 1024) {
    float v = candv_g[p];
    int ix = candi_g[p];
    atomicOr(&bmCand[ix >> 5], 1u << (ix & 31));
    int b = (int)(v * 1024.0f);
    if (b > 255) b = 255;
    int pos = atomicAdd(&bcnt[b], 1);
    if (pos < 24) { bV[b * 24 + pos] = v; bI[b * 24 + pos] = ix; }
  }
  __syncthreads();
  if (t < 256) {
    int n = bcnt[t]; if (n > 24) n = 24;
    bcnt[t] = n;
    bpre[t] = n;
  }
  __syncthreads();
  for (int s2 = 1; s2 < 256; s2 <<= 1) {
    int add = 0;
    if (t < 256 && t >= s2) add = bpre[t - s2];
    __syncthreads();
    if (t < 256) bpre[t] += add;
    __syncthreads();
  }
  if (t < 256) {
    int n = bcnt[t];
    float* bv = bV + t * 24;
    int* bi = bI + t * 24;
    for (int a = 1; a < n; ++a) {
      float v = bv[a]; int ix = bi[a];
      int p = a - 1;
      while (p >= 0) {
        float vp = bv[p];
        int ip = bi[p];
        if (vp < v || (vp == v && ip < ix)) break;
        bv[p + 1] = vp; bi[p + 1] = ip;
        --p;
      }
      bv[p + 1] = v; bi[p + 1] = ix;
    }
    if (t == 255) totsh = bpre[255];
  }
  __syncthreads();
  if (t < 256) {
    int n = bcnt[t];
    int off = bpre[t] - n;
    for (int k = 0; k < n; ++k) {
      int ix = bI[t * 24 + k];
      int tag = (bmSeen[ix >> 5] >> (ix & 31)) & 1;
      si[off + k] = ix | (tag << 30);
    }
  }
  __syncthreads();
  int nc = totsh;
  if (nc < 1) nc = 1;
  if (t < 64) {
    const int lane = t;
    const double sum0 = dred[0];
    int mreg[8]; unsigned ureg[8];
#pragma unroll
    for (int g = 0; g < 8; ++g) {
      const int i = g * 64 + lane;
      int m = mx[i];
      float um = umx[i];
      unsigned bit = 1u << (m & 31);
      bool dirty = ((bmDup[m >> 5] | bmCand[m >> 5]) & bit) != 0;
      float mean = (float)((sum0 + (double)i) * (1.0 / 65536.0));
      bool dec = um < mean;
      mreg[g] = m | (dirty ? 0x10000 : 0) | (dec ? 0x20000 : 0);
      ureg[g] = __float_as_uint(um);
    }
    int ptr = 0;
    int c0 = si[0], c1 = si[1], c2 = si[2], c3 = si[3];

#define SCAN_STEP(G, J)                                                       \
  {                                                                           \
    const int I = (G) * 64 + (J);                                             \
    const int RM = __builtin_amdgcn_readlane(mreg[G], (J));                   \
    const int mxi = RM & 0xFFFF;                                              \
    const int fl = (RM >> 16) & 3;                                            \
    int sel, chain; bool adv;                                                 \
    if (!(fl & 1)) {                                                          \
      if (fl & 2) { sel = mxi; chain = 0; adv = false; }                      \
      else { sel = c0 & 0xFFFF; chain = 0; adv = true; }                      \
    } else {                                                                  \
      const float RU = __uint_as_float(__builtin_amdgcn_readlane(ureg[G], (J))); \
      const int cc = (int)cnt8[mxi];                                          \
      const float mean = (float)((sum0 + (double)I) * (1.0 / 65536.0));       \
      const float uu = RU + (float)cc;                                        \
      const int cand_i = c0 & 0xFFFF;                                         \
      if (uu < mean) { sel = mxi; chain = cc; adv = (mxi == cand_i); }        \
      else { sel = cand_i; chain = 0; adv = true; }                           \
    }                                                                         \
    if (lane == 0) {                                                          \
      cnt8[sel] = (unsigned char)(chain + 1);                                 \
      idxl[I] = sel;                                                          \
      chl[I] = chain;                                                         \
    }                                                                         \
    if (adv) {                                                                \
      for (;;) {                                                              \
        ++ptr;                                                                \
        if (ptr >= nc) {                                                      \
          ptr = nc - 1;                                                       \
          c0 = si[ptr];                                                       \
          c1 = si[ptr + 1 < 2048 ? ptr + 1 : 2047];                           \
          c2 = si[ptr + 2 < 2048 ? ptr + 2 : 2047];                           \
          c3 = si[ptr + 3 < 2048 ? ptr + 3 : 2047];                           \
          break;                                                              \
        }                                                                     \
        c0 = c1; c1 = c2; c2 = c3;                                            \
        c3 = si[ptr + 3 < 2048 ? ptr + 3 : 2047];                             \
        if (!(c0 & (1 << 30))) break;                                         \
        if (cnt8[c0 & 0xFFFF] == 0) break;                                    \
      }                                                                       \
    }                                                                         \
  }

#pragma unroll
    for (int g = 0; g < 8; ++g) {
      for (int j = 0; j < 64; j += 4) {
        SCAN_STEP(g, j + 0);
        SCAN_STEP(g, j + 1);
        SCAN_STEP(g, j + 2);
        SCAN_STEP(g, j + 3);
      }
    }
#undef SCAN_STEP
  }
  __syncthreads();
  if (t < 512) {
    idxA[t] = idxl[t];
    chainA[t] = chl[t];
  }
  for (int p = t; p < 65536; p += 1024) {
    int c = (int)cnt8[p];
    if (c > 0) new_usage[p] = usage[p] + (float)c;
  }
}

// ============ parallel gate for first-occurrence steps ============
__global__ void k_gate0(const int* __restrict__ idxA, const int* __restrict__ chainA,
                        const float* __restrict__ memory, const float* __restrict__ query,
                        const float* __restrict__ Gq, const float* __restrict__ Gr,
                        const float* __restrict__ Wg, float* __restrict__ new_memory) {
  const int i = blockIdx.x;
  if (chainA[i] != 0) return;
  const int sel = idxA[i];
  __shared__ __align__(16) float oldr[256];
  const int d = threadIdx.x;
  oldr[d] = memory[(size_t)sel * 256 + d];
  __syncthreads();
  const float4* wg = reinterpret_cast<const float4*>(Wg + (size_t)d * 768 + 256);
  float acc = Gq[(size_t)i * 256 + d] + Gr[(size_t)i * 256 + d];
#pragma unroll 8
  for (int j4 = 0; j4 < 64; ++j4) {
    float4 w = wg[j4];
    float4 o = *reinterpret_cast<const float4*>(&oldr[j4 * 4]);
    acc += w.x * o.x + w.y * o.y + w.z * o.z + w.w * o.w;
  }
  float g = 1.0f / (1.0f + __expf(-acc));
  new_memory[(size_t)sel * 256 + d] = g * query[(size_t)i * 256 + d] + (1.0f - g) * oldr[d];
}

// ============ chained steps: one block per chained slot, serial within slot ============
__global__ void k_chain(const int* __restrict__ idxA, const int* __restrict__ chainA,
                        const float* __restrict__ query, const float* __restrict__ Gq,
                        const float* __restrict__ Gr, const float* __restrict__ Wg,
                        float* __restrict__ new_memory) {
  __shared__ int flags[512];
  __shared__ int idxs[512];
  __shared__ __align__(16) float oldr[256];
  const int j0 = blockIdx.x;
  const int d = threadIdx.x;
  flags[d] = chainA[d]; flags[d + 256] = chainA[d + 256];
  idxs[d] = idxA[d]; idxs[d + 256] = idxA[d + 256];
  __syncthreads();
  if (flags[j0] != 1) return;
  const int slot = idxs[j0];
  for (int i = j0; i < 512; ++i) {
    if (idxs[i] != slot) continue;
    oldr[d] = new_memory[(size_t)slot * 256 + d];
    __syncthreads();
    const float4* wg = reinterpret_cast<const float4*>(Wg + (size_t)d * 768 + 256);
    float acc = Gq[(size_t)i * 256 + d] + Gr[(size_t)i * 256 + d];
#pragma unroll 8
    for (int j4 = 0; j4 < 64; ++j4) {
      float4 w = wg[j4];
      float4 o = *reinterpret_cast<const float4*>(&oldr[j4 * 4]);
      acc += w.x * o.x + w.y * o.y + w.z * o.z + w.w * o.w;
    }
    float g = 1.0f / (1.0f + __expf(-acc));
    new_memory[(size_t)slot * 256 + d] = g * query[(size_t)i * 256 + d] + (1.0f - g) * oldr[d];
    __threadfence();
    __syncthreads();
  }
}

extern "C" void kernel_launch(void* const* d_in, const int* in_sizes, int n_in,
                              void* d_out, int out_size, void* d_ws, size_t ws_size,
                              hipStream_t stream) {
  const float* query  = (const float*)d_in[0];
  const float* memory = (const float*)d_in[1];
  const float* Wq = (const float*)d_in[2];
  const float* bq = (const float*)d_in[3];
  const float* Wk = (const float*)d_in[4];
  const float* bk = (const float*)d_in[5];
  const float* Wv = (const float*)d_in[6];
  const float* bv = (const float*)d_in[7];
  const float* Wo = (const float*)d_in[8];
  const float* bo = (const float*)d_in[9];
  const float* Wg = (const float*)d_in[10];
  const float* bg = (const float*)d_in[11];
  const float* usage = (const float*)d_in[12];

  float* out = (float*)d_out;
  float* retr_out = out;
  float* newmem = out + 131072;
  float* newusage = out + 131072 + 16777216;
  float* part2 = newmem;                                      // [64][512][256] f32 (32 MB)
  unsigned short* VT = (unsigned short*)(newmem + 8388608);   // [256][65536] bf16 (32 MB)

  float* ws = (float*)d_ws;
  float* Qb    = ws + OFF_Q;
  float* Gqb   = ws + OFF_GQ;
  float* Grb   = ws + OFF_GR;
  float* Rpreb = ws + OFF_RPRE;
  unsigned short* QBF   = (unsigned short*)(ws + OFF_QBF);
  unsigned short* WKBF  = (unsigned short*)(ws + OFF_WKBF);
  unsigned short* WVBF  = (unsigned short*)(ws + OFF_WVBF);
  unsigned short* KB    = (unsigned short*)(ws + OFF_KB);
  float* ZPb   = ws + OFF_ZP;
  float* AMVb  = ws + OFF_AMV;
  int*   AMIb  = (int*)(ws + OFF_AMI);
  int*   MXb   = (int*)(ws + OFF_MX);
  float* UMXb  = ws + OFF_UMX;
  float* CANDVb = ws + OFF_CANDV;
  int*   CANDIb = (int*)(ws + OFF_CANDI);
  float* BSUMb  = ws + OFF_BSUM;
  int*   CNTb   = (int*)(ws + OFF_CNT);
  int*   IDXAb  = (int*)(ws + OFF_IDXA);
  int*   CHAINb = (int*)(ws + OFF_CHAIN);

  hipMemsetAsync(CNTb, 0, sizeof(int), stream);

  k_cvt<<<32, 256, 0, stream>>>(Wk, WKBF, 65536);
  k_cvt<<<32, 256, 0, stream>>>(Wv, WVBF, 65536);
  // projmm (0..1023) || qgq (1024..1535)
  k_projq<<<1536, 256, 0, stream>>>(memory, WKBF, bk, WVBF, bv, KB, VT,
                                    query, Wq, bq, Wg, bg, Qb, Gqb, QBF);
  k_fused<<<dim3(64, 8), 256, 0, stream>>>(QBF, KB, VT, part2, ZPb, AMVb, AMIb);
  // amax2 (0..511) || cand (512..767) || rcomb+Z (768..1279)
  k_par0<<<1280, 256, 0, stream>>>(Qb, Wk, bk, memory, ZPb, AMVb, AMIb, usage,
                                   MXb, UMXb, CANDVb, CANDIb, CNTb, BSUMb,
                                   part2, Rpreb);

  hipMemcpyAsync(newusage, usage, (size_t)65536 * 4, hipMemcpyDeviceToDevice, stream);

  // scan (0) || out1 (1..128) || full newmem copy (129..1152)
  k_par1<<<1153, 1024, 0, stream>>>(CANDVb, CANDIb, CNTb, BSUMb, MXb, UMXb, usage,
                                    IDXAb, CHAINb, newusage, Rpreb, Wo, bo, Wg,
                                    retr_out, Grb, memory, newmem);

  k_gate0<<<512, 256, 0, stream>>>(IDXAb, CHAINb, memory, query, Gqb, Grb, Wg, newmem);
  k_chain<<<512, 256, 0, stream>>>(IDXAb, CHAINb, query, Gqb, Grb, Wg, newmem);
}

// Round 16
// 396.640 us; speedup vs baseline: 1.2556x; 1.0128x over previous
//
#include <hip/hip_runtime.h>
#include <hip/hip_bf16.h>
#include <math.h>

// ---- workspace layout (float offsets) ----
static const size_t OFF_Q     = 0;          // [512][256] f32
static const size_t OFF_GQ    = 131072;     // [512][256] f32
static const size_t OFF_GR    = 262144;     // [512][256] f32
static const size_t OFF_RPRE  = 393216;     // [512][256] f32
static const size_t OFF_QBF   = 524288;     // [512][256] bf16 (65536 f32 slots)
static const size_t OFF_WKBF  = 8978432;    // [256][256] bf16 (32768 slots)
static const size_t OFF_WVBF  = 9011200;    // [256][256] bf16 (32768 slots)
static const size_t OFF_KB    = 9043968;    // [65536][256] bf16 (8388608 slots)
static const size_t OFF_ZP    = 17432576;   // [4][512][64] f32 (Z partials)
static const size_t OFF_AMV   = 17698816;   // [64][512][2] f32
static const size_t OFF_AMI   = 17764352;   // [64][512][2] i32
static const size_t OFF_MX    = 17829888;   // [512] i32
static const size_t OFF_UMX   = 17830400;   // [512] f32
static const size_t OFF_CANDV = 17830912;   // [2048] f32
static const size_t OFF_CANDI = 17835008;   // [2048] i32
static const size_t OFF_BSUM  = 17839104;   // [256] f32
static const size_t OFF_CNT   = 17839360;   // [16] i32
static const size_t OFF_IDXA  = 17839376;   // [512] i32
static const size_t OFF_CHAIN = 17839888;   // [512] i32

typedef short v8s __attribute__((ext_vector_type(8)));
typedef float f32x4 __attribute__((ext_vector_type(4)));

__device__ __forceinline__ unsigned short f2bf(float f) {
  unsigned int x = __float_as_uint(f);
  unsigned int r = (x + 0x7fffu + ((x >> 16) & 1u)) >> 16;
  return (unsigned short)r;
}

// async global->LDS DMA, 16 B per lane; LDS dest = wave-uniform base + lane*16
__device__ __forceinline__ void gld16(const void* g, void* l) {
  __builtin_amdgcn_global_load_lds(
      (const __attribute__((address_space(1))) void*)g,
      (__attribute__((address_space(3))) void*)l, 16, 0, 0);
}

// ============ cvt: fp32 -> bf16 for Wk (blocks 0..31) and Wv (32..63); zeroes cnt ============
__global__ void k_cvt2(const float* __restrict__ Wk, const float* __restrict__ Wv,
                       unsigned short* __restrict__ outK, unsigned short* __restrict__ outV,
                       int* __restrict__ cnt) {
  const int bid = blockIdx.x, t = threadIdx.x;
  if (bid == 0 && t == 0) cnt[0] = 0;
  const float* in = (bid < 32) ? Wk : Wv;
  unsigned short* out = (bid < 32) ? outK : outV;
  int i = ((bid & 31) * 256 + t) * 8;
  float4 a = *reinterpret_cast<const float4*>(in + i);
  float4 b = *reinterpret_cast<const float4*>(in + i + 4);
  ushort4 o1 = {f2bf(a.x), f2bf(a.y), f2bf(a.z), f2bf(a.w)};
  ushort4 o2 = {f2bf(b.x), f2bf(b.y), f2bf(b.z), f2bf(b.w)};
  *reinterpret_cast<ushort4*>(out + i) = o1;
  *reinterpret_cast<ushort4*>(out + i + 4) = o2;
}

// ============ PROJQ: blocks 0..1023 = MFMA K/V projection; 1024..1535 = Q/Gq GEMVs ============
__global__ __launch_bounds__(256) void k_projq(const float* __restrict__ mem,
    const unsigned short* __restrict__ Wkbf, const float* __restrict__ bk,
    const unsigned short* __restrict__ Wvbf, const float* __restrict__ bv,
    unsigned short* __restrict__ Kout, unsigned short* __restrict__ Vt,
    const float* __restrict__ query, const float* __restrict__ Wq,
    const float* __restrict__ bq, const float* __restrict__ Wg,
    const float* __restrict__ bg, float* __restrict__ Q,
    float* __restrict__ Gq, unsigned short* __restrict__ Qbf) {
  __shared__ __align__(16) char sbuf[36864];
  const int bid = blockIdx.x;
  const int t = threadIdx.x;

  if (bid >= 1024) {
    // ---- qgq: Q = query@Wq.T + bq (f32 + bf16*0.125) ; Gq = query@Wg[:,0:256].T + bg ----
    float* qrow = reinterpret_cast<float*>(sbuf);
    const int i = bid - 1024;
    const int d = t;
    qrow[d] = query[(size_t)i * 256 + d];
    __syncthreads();
    const float4* wq = reinterpret_cast<const float4*>(Wq + (size_t)d * 256);
    float acc = 0.f;
#pragma unroll 8
    for (int j4 = 0; j4 < 64; ++j4) {
      float4 w = wq[j4];
      float4 q = *reinterpret_cast<const float4*>(&qrow[j4 * 4]);
      acc += w.x * q.x + w.y * q.y + w.z * q.z + w.w * q.w;
    }
    float qv = acc + bq[d];
    Q[(size_t)i * 256 + d] = qv;
    Qbf[(size_t)i * 256 + d] = f2bf(qv * 0.125f);
    const float4* wg = reinterpret_cast<const float4*>(Wg + (size_t)d * 768);
    float acc2 = 0.f;
#pragma unroll 8
    for (int j4 = 0; j4 < 64; ++j4) {
      float4 w = wg[j4];
      float4 q = *reinterpret_cast<const float4*>(&qrow[j4 * 4]);
      acc2 += w.x * q.x + w.y * q.y + w.z * q.z + w.w * q.w;
    }
    Gq[(size_t)i * 256 + d] = acc2 + bg[d];
    return;
  }

  // ---- projmm ----
  const int w = t >> 6, l = t & 63, l15 = l & 15, lg = l >> 4;
  const int mb = bid * 64;
  const int mrow = mb + w * 16 + l15;
  v8s am[8];
#pragma unroll
  for (int kk = 0; kk < 8; ++kk) {
    const float* src = mem + (size_t)mrow * 256 + kk * 32 + lg * 8;
    float4 f0 = *reinterpret_cast<const float4*>(src);
    float4 f1 = *reinterpret_cast<const float4*>(src + 4);
    v8s a;
    a[0] = (short)f2bf(f0.x); a[1] = (short)f2bf(f0.y);
    a[2] = (short)f2bf(f0.z); a[3] = (short)f2bf(f0.w);
    a[4] = (short)f2bf(f1.x); a[5] = (short)f2bf(f1.y);
    a[6] = (short)f2bf(f1.z); a[7] = (short)f2bf(f1.w);
    am[kk] = a;
  }

#define STAGE_W(Wsrc, dt)                                                     \
  {                                                                           \
    _Pragma("unroll")                                                         \
    for (int j = 0; j < 8; ++j) {                                             \
      int off = j * 4096 + w * 1024 + l * 16;                                 \
      int row = off >> 9;                                                     \
      int col = off & 511;                                                    \
      gld16(reinterpret_cast<const char*>(Wsrc) +                             \
                (size_t)((dt) * 64 + row) * 512 + (col ^ ((row & 7) << 4)),   \
            sbuf + j * 4096 + w * 1024);                                      \
    }                                                                         \
  }

  // ---- K = mem @ Wk^T + bk ----
  {
    f32x4 acc[16];
#pragma unroll
    for (int df = 0; df < 16; ++df) {
      float bz = bk[df * 16 + l15];
      acc[df] = (f32x4){bz, bz, bz, bz};
    }
    for (int dt = 0; dt < 4; ++dt) {
      STAGE_W(Wkbf, dt);
      asm volatile("s_waitcnt vmcnt(0)" ::: "memory");
      __builtin_amdgcn_s_barrier();
#pragma unroll
      for (int kk = 0; kk < 8; ++kk)
#pragma unroll
        for (int dfl = 0; dfl < 4; ++dfl) {
          const int row = dfl * 16 + l15;
          const v8s b = *reinterpret_cast<const v8s*>(
              sbuf + row * 512 + ((kk * 64 + lg * 16) ^ ((row & 7) << 4)));
          acc[dt * 4 + dfl] =
              __builtin_amdgcn_mfma_f32_16x16x32_bf16(am[kk], b, acc[dt * 4 + dfl], 0, 0, 0);
        }
      asm volatile("" ::: "memory");
      __builtin_amdgcn_s_barrier();
    }
    unsigned short* bounce = reinterpret_cast<unsigned short*>(sbuf);
#pragma unroll
    for (int df = 0; df < 16; ++df)
#pragma unroll
      for (int r = 0; r < 4; ++r)
        bounce[(w * 16 + lg * 4 + r) * 264 + df * 16 + l15] = f2bf(acc[df][r]);
  }
  __syncthreads();
  {
    unsigned short* bounce = reinterpret_cast<unsigned short*>(sbuf);
    int row = t >> 2, quad = t & 3;
    const uint4* src = reinterpret_cast<const uint4*>(&bounce[row * 264 + quad * 64]);
    uint4* dst = reinterpret_cast<uint4*>(Kout + (size_t)(mb + row) * 256 + quad * 64);
#pragma unroll
    for (int x = 0; x < 8; ++x) dst[x] = src[x];
  }
  __syncthreads();
  // ---- V = mem @ Wv^T + bv, stored transposed Vt[d][m] ----
  {
    f32x4 acc[16];
#pragma unroll
    for (int df = 0; df < 16; ++df) {
      float bz = bv[df * 16 + l15];
      acc[df] = (f32x4){bz, bz, bz, bz};
    }
    for (int dt = 0; dt < 4; ++dt) {
      STAGE_W(Wvbf, dt);
      asm volatile("s_waitcnt vmcnt(0)" ::: "memory");
      __builtin_amdgcn_s_barrier();
#pragma unroll
      for (int kk = 0; kk < 8; ++kk)
#pragma unroll
        for (int dfl = 0; dfl < 4; ++dfl) {
          const int row = dfl * 16 + l15;
          const v8s b = *reinterpret_cast<const v8s*>(
              sbuf + row * 512 + ((kk * 64 + lg * 16) ^ ((row & 7) << 4)));
          acc[dt * 4 + dfl] =
              __builtin_amdgcn_mfma_f32_16x16x32_bf16(am[kk], b, acc[dt * 4 + dfl], 0, 0, 0);
        }
      asm volatile("" ::: "memory");
      __builtin_amdgcn_s_barrier();
    }
    unsigned short* bounce = reinterpret_cast<unsigned short*>(sbuf);
#pragma unroll
    for (int df = 0; df < 16; ++df)
#pragma unroll
      for (int r = 0; r < 4; ++r)
        bounce[(df * 16 + l15) * 72 + w * 16 + lg * 4 + r] = f2bf(acc[df][r]);
  }
  __syncthreads();
  {
    const unsigned short* bounce = reinterpret_cast<const unsigned short*>(sbuf);
    const uint4* src = reinterpret_cast<const uint4*>(&bounce[t * 72]);
    uint4* dst = reinterpret_cast<uint4*>(Vt + (size_t)t * 65536 + mb);
#pragma unroll
    for (int x = 0; x < 8; ++x) dst[x] = src[x];
  }
#undef STAGE_W
}

// ============ FUSED pass: scores + no-max exp + Z accumulation + PV + top-2 ============
__global__ __launch_bounds__(256, 2) void k_fused(const unsigned short* __restrict__ Qbf,
    const unsigned short* __restrict__ Kb, const unsigned short* __restrict__ Vt,
    float* __restrict__ part2, float* __restrict__ zpart,
    float* __restrict__ amv, int* __restrict__ ami) {
  __shared__ __align__(16) unsigned short KsBuf[2][8192];
  __shared__ __align__(16) unsigned short VsBuf[2][8192];
  __shared__ __align__(16) unsigned short Pl[4][16][40];
  const int mc = blockIdx.x;   // 0..63
  const int qc = blockIdx.y;   // 0..7
  const int t = threadIdx.x;
  const int w = t >> 6, l = t & 63, l15 = l & 15, lg = l >> 4;
  const int qbase = qc * 64 + w * 16;
  const char* Kbc = reinterpret_cast<const char*>(Kb);
  const char* Vtc = reinterpret_cast<const char*>(Vt);
  char* lds_k = reinterpret_cast<char*>(KsBuf);
  char* lds_v = reinterpret_cast<char*>(VsBuf);
  v8s aq[4][2];
#pragma unroll
  for (int h = 0; h < 4; ++h)
#pragma unroll
    for (int kk = 0; kk < 2; ++kk)
      aq[h][kk] = *reinterpret_cast<const v8s*>(
          Qbf + (size_t)(qbase + l15) * 256 + h * 64 + kk * 32 + lg * 8);
  f32x4 racc[4][4] = {};
  float zs[4][4] = {};
  float v1[4], v2[4]; int i1[4], i2[4];
#pragma unroll
  for (int r = 0; r < 4; ++r) { v1[r] = -INFINITY; v2[r] = -INFINITY; i1[r] = 0x7fffffff; i2[r] = 0x7fffffff; }
  const int mbase = mc * 1024;

#define STAGE_K2(bufsel, m0)                                                  \
  {                                                                           \
    _Pragma("unroll")                                                         \
    for (int j = 0; j < 4; ++j) {                                             \
      int off = w * 4096 + j * 1024 + l * 16;                                 \
      int row = off >> 9;                                                     \
      int col = off & 511;                                                    \
      gld16(Kbc + (size_t)((m0) + row) * 512 + (col ^ ((row & 7) << 4)),      \
            lds_k + (bufsel) * 16384 + w * 4096 + j * 1024);                  \
    }                                                                         \
  }
#define STAGE_V2(bufsel, m0)                                                  \
  {                                                                           \
    _Pragma("unroll")                                                         \
    for (int j = 0; j < 4; ++j) {                                             \
      int off = w * 4096 + j * 1024 + l * 16;                                 \
      int row = off >> 6;                                                     \
      int col = off & 63;                                                     \
      gld16(Vtc + (size_t)row * 131072 + (size_t)(m0) * 2 +                   \
                (col ^ (((row >> 1) & 3) << 4)),                              \
            lds_v + (bufsel) * 16384 + w * 4096 + j * 1024);                  \
    }                                                                         \
  }

  STAGE_K2(0, mbase);
  STAGE_V2(0, mbase);
  for (int mt = 0; mt < 32; ++mt) {
    const int m0 = mbase + mt * 32;
    if (mt < 31) {
      STAGE_K2((mt + 1) & 1, m0 + 32);
      STAGE_V2((mt + 1) & 1, m0 + 32);
      asm volatile("s_waitcnt vmcnt(8)" ::: "memory");
    } else {
      asm volatile("s_waitcnt vmcnt(0)" ::: "memory");
    }
    __builtin_amdgcn_s_barrier();
    const char* kbp = lds_k + (mt & 1) * 16384;
    const char* vbp = lds_v + (mt & 1) * 16384;
    float cacc[4][2] = {};
#pragma unroll
    for (int h = 0; h < 4; ++h) {
      f32x4 sacc[2] = {};
#pragma unroll
      for (int nf = 0; nf < 2; ++nf) {
        const int row = nf * 16 + l15;
        const int sw = (row & 7) << 4;
#pragma unroll
        for (int kk = 0; kk < 2; ++kk) {
          const v8s b = *reinterpret_cast<const v8s*>(
              kbp + row * 512 + ((h * 128 + kk * 64 + lg * 16) ^ sw));
          sacc[nf] = __builtin_amdgcn_mfma_f32_16x16x32_bf16(aq[h][kk], b, sacc[nf], 0, 0, 0);
        }
      }
#pragma unroll
      for (int nf = 0; nf < 2; ++nf)
#pragma unroll
        for (int r = 0; r < 4; ++r) {
          float e = __expf(sacc[nf][r]);     // scores pre-scaled by 0.125 via Qbf
          cacc[r][nf] += e;
          zs[r][h] += e;
          Pl[w][lg * 4 + r][nf * 16 + l15] =
              (unsigned short)(__float_as_uint(e) >> 16);
        }
      const v8s pa = *reinterpret_cast<const v8s*>(
          reinterpret_cast<const char*>(&Pl[w][l15][0]) + lg * 16);
#pragma unroll
      for (int df = 0; df < 4; ++df) {
        const int vrow = h * 64 + df * 16 + l15;
        const v8s vb = *reinterpret_cast<const v8s*>(
            vbp + vrow * 64 + ((lg * 16) ^ (((vrow >> 1) & 3) << 4)));
        racc[h][df] = __builtin_amdgcn_mfma_f32_16x16x32_bf16(pa, vb, racc[h][df], 0, 0, 0);
      }
    }
#pragma unroll
    for (int r = 0; r < 4; ++r)
#pragma unroll
      for (int nf = 0; nf < 2; ++nf) {
        float val = cacc[r][nf];
        int idx = m0 + nf * 16 + l15;
        if (val > v1[r] || (val == v1[r] && idx < i1[r])) {
          v2[r] = v1[r]; i2[r] = i1[r]; v1[r] = val; i1[r] = idx;
        } else if (val > v2[r] || (val == v2[r] && idx < i2[r])) {
          v2[r] = val; i2[r] = idx;
        }
      }
    asm volatile("" ::: "memory");
    __builtin_amdgcn_s_barrier();
  }
#undef STAGE_K2
#undef STAGE_V2
#pragma unroll
  for (int h = 0; h < 4; ++h)
#pragma unroll
    for (int df = 0; df < 4; ++df)
#pragma unroll
      for (int r = 0; r < 4; ++r) {
        int q = qbase + lg * 4 + r;
        part2[(size_t)mc * 131072 + (size_t)q * 256 + h * 64 + df * 16 + l15] = racc[h][df][r];
      }
#pragma unroll
  for (int mask = 1; mask <= 8; mask <<= 1)
#pragma unroll
    for (int r = 0; r < 4; ++r)
#pragma unroll
      for (int h = 0; h < 4; ++h)
        zs[r][h] += __shfl_xor(zs[r][h], mask);
  if (l15 == 0) {
#pragma unroll
    for (int r = 0; r < 4; ++r)
#pragma unroll
      for (int h = 0; h < 4; ++h) {
        int q = qbase + lg * 4 + r;
        zpart[((size_t)h * 512 + q) * 64 + mc] = zs[r][h];
      }
  }
#pragma unroll
  for (int mask = 1; mask <= 8; mask <<= 1) {
#pragma unroll
    for (int r = 0; r < 4; ++r) {
      float ov1 = __shfl_xor(v1[r], mask); int oi1 = __shfl_xor(i1[r], mask);
      float ov2 = __shfl_xor(v2[r], mask); int oi2 = __shfl_xor(i2[r], mask);
      bool cGTa = ov1 > v1[r] || (ov1 == v1[r] && oi1 < i1[r]);
      float nv1, nv2; int ni1, ni2;
      if (cGTa) {
        nv1 = ov1; ni1 = oi1;
        bool aGTd = v1[r] > ov2 || (v1[r] == ov2 && i1[r] < oi2);
        nv2 = aGTd ? v1[r] : ov2; ni2 = aGTd ? i1[r] : oi2;
      } else {
        nv1 = v1[r]; ni1 = i1[r];
        bool bGTc = v2[r] > ov1 || (v2[r] == ov1 && i2[r] < oi1);
        nv2 = bGTc ? v2[r] : ov1; ni2 = bGTc ? i2[r] : oi1;
      }
      v1[r] = nv1; i1[r] = ni1; v2[r] = nv2; i2[r] = ni2;
    }
  }
  if (l15 == 0) {
#pragma unroll
    for (int r = 0; r < 4; ++r) {
      int q = qbase + lg * 4 + r;
      amv[((size_t)mc * 512 + q) * 2] = v1[r];
      amv[((size_t)mc * 512 + q) * 2 + 1] = v2[r];
      ami[((size_t)mc * 512 + q) * 2] = i1[r];
      ami[((size_t)mc * 512 + q) * 2 + 1] = i2[r];
    }
  }
}

// ============ PAR0: amax2 (0..511) | cand (512..767) | rcomb+Z (768..1279) ============
__global__ __launch_bounds__(256) void k_par0(const float* __restrict__ Qf,
    const float* __restrict__ Wk, const float* __restrict__ bk,
    const float* __restrict__ memory, const float* __restrict__ zpart,
    const float* __restrict__ amv, const int* __restrict__ ami,
    const float* __restrict__ usage, int* __restrict__ mx, float* __restrict__ umx,
    float* __restrict__ candv, int* __restrict__ candi, int* __restrict__ cnt,
    float* __restrict__ bsum, const float* __restrict__ part2,
    float* __restrict__ rpre) {
  __shared__ float u[4][256];
  __shared__ float ch[4];
  __shared__ float qrow[256];
  __shared__ float redv[4];
  __shared__ int redi[4];
  __shared__ float zish[4];
  const int bid = blockIdx.x;
  const int t = threadIdx.x;

  if (bid >= 768) {
    // ---- rcomb with inline Z ----
    const int b = bid - 768;
    const int h = t >> 6, c = t & 63;
    float z = zpart[((size_t)h * 512 + b) * 64 + c];
#pragma unroll
    for (int mask = 32; mask >= 1; mask >>= 1) z += __shfl_xor(z, mask);
    const float iZ = 1.0f / z;
    const int d = t;
    float s = 0.f;
    for (int cc = 0; cc < 64; ++cc) s += part2[(size_t)cc * 131072 + (size_t)b * 256 + d];
    rpre[(size_t)b * 256 + d] = s * iZ;
    return;
  }
  if (bid >= 512) {
    // ---- cand ----
    float* sred = qrow;
    int g = (bid - 512) * 256 + t;
    float uu = usage[g];
    sred[t] = uu;
    __syncthreads();
    for (int s = 128; s > 0; s >>= 1) {
      if (t < s) sred[t] += sred[t + s];
      __syncthreads();
    }
    if (t == 0) bsum[bid - 512] = sred[0];
    if (uu < 0.25f) {
      int pos = atomicAdd(cnt, 1);
      if (pos < 2048) { candv[pos] = uu; candi[pos] = g; }
    }
    return;
  }

  // ---- amax2 with inline Z ----
  const int row = bid;
  {
    const int h = t >> 6, c = t & 63;
    float z = zpart[((size_t)h * 512 + row) * 64 + c];
#pragma unroll
    for (int mask = 32; mask >= 1; mask >>= 1) z += __shfl_xor(z, mask);
    if (c == 0) zish[h] = 1.0f / z;
  }
  qrow[t] = Qf[(size_t)row * 256 + t];
  __syncthreads();
#pragma unroll
  for (int h = 0; h < 4; ++h) {
    float s = 0.f;
    for (int d = 0; d < 64; ++d) s += qrow[h * 64 + d] * Wk[(size_t)(h * 64 + d) * 256 + t];
    u[h][t] = s;
  }
  if (t < 4) {
    float s = 0.f;
    for (int d = 0; d < 64; ++d) s += qrow[t * 64 + d] * bk[t * 64 + d];
    ch[t] = s;
  }
  __syncthreads();
  const int wv = t >> 6, ln = t & 63;
  const float Zi0 = zish[0], Zi1 = zish[1], Zi2 = zish[2], Zi3 = zish[3];
  float bestv = -INFINITY; int besti = 0x7fffffff;
  for (int c = wv; c < 128; c += 4) {
    int m = ami[((size_t)(c >> 1) * 512 + row) * 2 + (c & 1)];
    float s0 = 0.f, s1 = 0.f, s2 = 0.f, s3 = 0.f;
#pragma unroll
    for (int k = 0; k < 4; ++k) {
      float mv = memory[(size_t)m * 256 + ln + 64 * k];
      s0 += mv * u[0][ln + 64 * k];
      s1 += mv * u[1][ln + 64 * k];
      s2 += mv * u[2][ln + 64 * k];
      s3 += mv * u[3][ln + 64 * k];
    }
#pragma unroll
    for (int mask = 32; mask >= 1; mask >>= 1) {
      s0 += __shfl_xor(s0, mask); s1 += __shfl_xor(s1, mask);
      s2 += __shfl_xor(s2, mask); s3 += __shfl_xor(s3, mask);
    }
    float a = __expf((s0 + ch[0]) * 0.125f) * Zi0 +
              __expf((s1 + ch[1]) * 0.125f) * Zi1 +
              __expf((s2 + ch[2]) * 0.125f) * Zi2 +
              __expf((s3 + ch[3]) * 0.125f) * Zi3;
    if (a > bestv || (a == bestv && m < besti)) { bestv = a; besti = m; }
  }
  if (ln == 0) { redv[wv] = bestv; redi[wv] = besti; }
  __syncthreads();
  if (t == 0) {
    float bv = -INFINITY; int bi = 0x7fffffff;
#pragma unroll
    for (int q = 0; q < 4; ++q) {
      if (redv[q] > bv || (redv[q] == bv && redi[q] < bi)) { bv = redv[q]; bi = redi[q]; }
    }
    mx[row] = bi;
    umx[row] = usage[bi];
  }
}

// ============ PAR1: scan (0) | out1 x4 rows (1..128) | full newmem copy (129..1152) ============
__global__ __launch_bounds__(1024) void k_par1(const float* __restrict__ candv_g,
    const int* __restrict__ candi_g, const int* __restrict__ cnt_g,
    const float* __restrict__ bsum, const int* __restrict__ mx,
    const float* __restrict__ umx, const float* __restrict__ usage,
    int* __restrict__ idxA, int* __restrict__ chainA, float* __restrict__ new_usage,
    const float* __restrict__ rpre, const float* __restrict__ Wo,
    const float* __restrict__ bo, const float* __restrict__ Wg,
    float* __restrict__ retr, float* __restrict__ Gr,
    const float* __restrict__ memory, float* __restrict__ newmem) {
  __shared__ float bV[256 * 24];
  __shared__ int   bI[256 * 24];
  __shared__ unsigned char cnt8[65536];
  __shared__ int si[2048];
  __shared__ unsigned int bmSeen[2048];
  __shared__ unsigned int bmDup[2048];
  __shared__ unsigned int bmCand[2048];
  __shared__ int idxl[512];
  __shared__ int chl[512];
  __shared__ int bcnt[256];
  __shared__ int bpre[256];
  __shared__ double dred[256];
  __shared__ int totsh;

  const int bid = blockIdx.x;
  const int t = threadIdx.x;

  if (bid >= 129) {
    const size_t base = (size_t)(bid - 129) * 16384 + (size_t)t * 16;
#pragma unroll
    for (int j = 0; j < 4; ++j) {
      size_t idx = base + (size_t)j * 4;
      *reinterpret_cast<float4*>(newmem + idx) =
          *reinterpret_cast<const float4*>(memory + idx);
    }
    return;
  }
  if (bid >= 1) {
    float* rr = bV;
    float* rf = bV + 1024;
    const int r4 = t >> 8, d = t & 255;
    const int i = (bid - 1) * 4 + r4;
    rr[r4 * 256 + d] = rpre[(size_t)i * 256 + d];
    __syncthreads();
    const float4* wo = reinterpret_cast<const float4*>(Wo + (size_t)d * 256);
    float acc = 0.f;
#pragma unroll 8
    for (int j4 = 0; j4 < 64; ++j4) {
      float4 w = wo[j4];
      float4 q = *reinterpret_cast<const float4*>(&rr[r4 * 256 + j4 * 4]);
      acc += w.x * q.x + w.y * q.y + w.z * q.z + w.w * q.w;
    }
    float v = acc + bo[d];
    retr[(size_t)i * 256 + d] = v;
    rf[r4 * 256 + d] = v;
    __syncthreads();
    const float4* wg = reinterpret_cast<const float4*>(Wg + (size_t)d * 768 + 512);
    float acc2 = 0.f;
#pragma unroll 8
    for (int j4 = 0; j4 < 64; ++j4) {
      float4 w = wg[j4];
      float4 q = *reinterpret_cast<const float4*>(&rf[r4 * 256 + j4 * 4]);
      acc2 += w.x * q.x + w.y * q.y + w.z * q.z + w.w * q.w;
    }
    Gr[(size_t)i * 256 + d] = acc2;
    return;
  }

  // ---- block 0: selection scan (v4) ----
  const int ncg0 = cnt_g[0];
  const int ncg = ncg0 > 2048 ? 2048 : ncg0;

  for (int p = t; p < 2048; p += 1024) {
    si[p] = 0; bmSeen[p] = 0u; bmDup[p] = 0u; bmCand[p] = 0u;
  }
  {
    uint4 z; z.x = 0u; z.y = 0u; z.z = 0u; z.w = 0u;
    uint4* c4 = reinterpret_cast<uint4*>(cnt8);
#pragma unroll
    for (int r = 0; r < 4; ++r) c4[t + r * 1024] = z;
  }
  if (t < 256) { bcnt[t] = 0; dred[t] = (double)bsum[t]; }
  __syncthreads();
  for (int s = 128; s > 0; s >>= 1) {
    if (t < s) dred[t] += dred[t + s];
    __syncthreads();
  }
  if (t < 512) {
    int m = mx[t];
    unsigned bit = 1u << (m & 31);
    unsigned old = atomicOr(&bmSeen[m >> 5], bit);
    if (old & bit) atomicOr(&bmDup[m >> 5], bit);
  }
  for (int p = t; p < ncg; p += 1024) {
    float v = candv_g[p];
    int ix = candi_g[p];
    atomicOr(&bmCand[ix >> 5], 1u << (ix & 31));
    int b = (int)(v * 1024.0f);
    if (b > 255) b = 255;
    int pos = atomicAdd(&bcnt[b], 1);
    if (pos < 24) { bV[b * 24 + pos] = v; bI[b * 24 + pos] = ix; }
  }
  __syncthreads();
  if (t < 256) {
    int n = bcnt[t]; if (n > 24) n = 24;
    bcnt[t] = n;
    bpre[t] = n;
  }
  __syncthreads();
  for (int s2 = 1; s2 < 256; s2 <<= 1) {
    int add = 0;
    if (t < 256 && t >= s2) add = bpre[t - s2];
    __syncthreads();
    if (t < 256) bpre[t] += add;
    __syncthreads();
  }
  if (t < 256) {
    int n = bcnt[t];
    float* bv = bV + t * 24;
    int* bi = bI + t * 24;
    for (int a = 1; a < n; ++a) {
      float v = bv[a]; int ix = bi[a];
      int p = a - 1;
      while (p >= 0) {
        float vp = bv[p];
        int ip = bi[p];
        if (vp < v || (vp == v && ip < ix)) break;
        bv[p + 1] = vp; bi[p + 1] = ip;
        --p;
      }
      bv[p + 1] = v; bi[p + 1] = ix;
    }
    if (t == 255) totsh = bpre[255];
  }
  __syncthreads();
  if (t < 256) {
    int n = bcnt[t];
    int off = bpre[t] - n;
    for (int k = 0; k < n; ++k) {
      int ix = bI[t * 24 + k];
      int tag = (bmSeen[ix >> 5] >> (ix & 31)) & 1;
      si[off + k] = ix | (tag << 30);
    }
  }
  __syncthreads();
  int nc = totsh;
  if (nc < 1) nc = 1;
  if (t < 64) {
    const int lane = t;
    const double sum0 = dred[0];
    int mreg[8]; unsigned ureg[8];
#pragma unroll
    for (int g = 0; g < 8; ++g) {
      const int i = g * 64 + lane;
      int m = mx[i];
      float um = umx[i];
      unsigned bit = 1u << (m & 31);
      bool dirty = ((bmDup[m >> 5] | bmCand[m >> 5]) & bit) != 0;
      float mean = (float)((sum0 + (double)i) * (1.0 / 65536.0));
      bool dec = um < mean;
      mreg[g] = m | (dirty ? 0x10000 : 0) | (dec ? 0x20000 : 0);
      ureg[g] = __float_as_uint(um);
    }
    int ptr = 0;
    int c0 = si[0], c1 = si[1], c2 = si[2], c3 = si[3];

#define SCAN_STEP(G, J)                                                       \
  {                                                                           \
    const int I = (G) * 64 + (J);                                             \
    const int RM = __builtin_amdgcn_readlane(mreg[G], (J));                   \
    const int mxi = RM & 0xFFFF;                                              \
    const int fl = (RM >> 16) & 3;                                            \
    int sel, chain; bool adv;                                                 \
    if (!(fl & 1)) {                                                          \
      if (fl & 2) { sel = mxi; chain = 0; adv = false; }                      \
      else { sel = c0 & 0xFFFF; chain = 0; adv = true; }                      \
    } else {                                                                  \
      const float RU = __uint_as_float(__builtin_amdgcn_readlane(ureg[G], (J))); \
      const int cc = (int)cnt8[mxi];                                          \
      const float mean = (float)((sum0 + (double)I) * (1.0 / 65536.0));       \
      const float uu = RU + (float)cc;                                        \
      const int cand_i = c0 & 0xFFFF;                                         \
      if (uu < mean) { sel = mxi; chain = cc; adv = (mxi == cand_i); }        \
      else { sel = cand_i; chain = 0; adv = true; }                           \
    }                                                                         \
    if (lane == 0) {                                                          \
      cnt8[sel] = (unsigned char)(chain + 1);                                 \
      idxl[I] = sel;                                                          \
      chl[I] = chain;                                                         \
    }                                                                         \
    if (adv) {                                                                \
      for (;;) {                                                              \
        ++ptr;                                                                \
        if (ptr >= nc) {                                                      \
          ptr = nc - 1;                                                       \
          c0 = si[ptr];                                                       \
          c1 = si[ptr + 1 < 2048 ? ptr + 1 : 2047];                           \
          c2 = si[ptr + 2 < 2048 ? ptr + 2 : 2047];                           \
          c3 = si[ptr + 3 < 2048 ? ptr + 3 : 2047];                           \
          break;                                                              \
        }                                                                     \
        c0 = c1; c1 = c2; c2 = c3;                                            \
        c3 = si[ptr + 3 < 2048 ? ptr + 3 : 2047];                             \
        if (!(c0 & (1 << 30))) break;                                         \
        if (cnt8[c0 & 0xFFFF] == 0) break;                                    \
      }                                                                       \
    }                                                                         \
  }

#pragma unroll
    for (int g = 0; g < 8; ++g) {
      for (int j = 0; j < 64; j += 4) {
        SCAN_STEP(g, j + 0);
        SCAN_STEP(g, j + 1);
        SCAN_STEP(g, j + 2);
        SCAN_STEP(g, j + 3);
      }
    }
#undef SCAN_STEP
  }
  __syncthreads();
  if (t < 512) {
    idxA[t] = idxl[t];
    chainA[t] = chl[t];
  }
  for (int p = t; p < 65536; p += 1024) {
    int c = (int)cnt8[p];
    if (c > 0) new_usage[p] = usage[p] + (float)c;
  }
}

// ============ parallel gate for first-occurrence steps ============
__global__ void k_gate0(const int* __restrict__ idxA, const int* __restrict__ chainA,
                        const float* __restrict__ memory, const float* __restrict__ query,
                        const float* __restrict__ Gq, const float* __restrict__ Gr,
                        const float* __restrict__ Wg, float* __restrict__ new_memory) {
  const int i = blockIdx.x;
  if (chainA[i] != 0) return;
  const int sel = idxA[i];
  __shared__ __align__(16) float oldr[256];
  const int d = threadIdx.x;
  oldr[d] = memory[(size_t)sel * 256 + d];
  __syncthreads();
  const float4* wg = reinterpret_cast<const float4*>(Wg + (size_t)d * 768 + 256);
  float acc = Gq[(size_t)i * 256 + d] + Gr[(size_t)i * 256 + d];
#pragma unroll 8
  for (int j4 = 0; j4 < 64; ++j4) {
    float4 w = wg[j4];
    float4 o = *reinterpret_cast<const float4*>(&oldr[j4 * 4]);
    acc += w.x * o.x + w.y * o.y + w.z * o.z + w.w * o.w;
  }
  float g = 1.0f / (1.0f + __expf(-acc));
  new_memory[(size_t)sel * 256 + d] = g * query[(size_t)i * 256 + d] + (1.0f - g) * oldr[d];
}

// ============ chained steps: one block per chained slot, serial within slot ============
__global__ void k_chain(const int* __restrict__ idxA, const int* __restrict__ chainA,
                        const float* __restrict__ query, const float* __restrict__ Gq,
                        const float* __restrict__ Gr, const float* __restrict__ Wg,
                        float* __restrict__ new_memory) {
  __shared__ int flags[512];
  __shared__ int idxs[512];
  __shared__ __align__(16) float oldr[256];
  const int j0 = blockIdx.x;
  const int d = threadIdx.x;
  flags[d] = chainA[d]; flags[d + 256] = chainA[d + 256];
  idxs[d] = idxA[d]; idxs[d + 256] = idxA[d + 256];
  __syncthreads();
  if (flags[j0] != 1) return;
  const int slot = idxs[j0];
  for (int i = j0; i < 512; ++i) {
    if (idxs[i] != slot) continue;
    oldr[d] = new_memory[(size_t)slot * 256 + d];
    __syncthreads();
    const float4* wg = reinterpret_cast<const float4*>(Wg + (size_t)d * 768 + 256);
    float acc = Gq[(size_t)i * 256 + d] + Gr[(size_t)i * 256 + d];
#pragma unroll 8
    for (int j4 = 0; j4 < 64; ++j4) {
      float4 w = wg[j4];
      float4 o = *reinterpret_cast<const float4*>(&oldr[j4 * 4]);
      acc += w.x * o.x + w.y * o.y + w.z * o.z + w.w * o.w;
    }
    float g = 1.0f / (1.0f + __expf(-acc));
    new_memory[(size_t)slot * 256 + d] = g * query[(size_t)i * 256 + d] + (1.0f - g) * oldr[d];
    __threadfence();
    __syncthreads();
  }
}

extern "C" void kernel_launch(void* const* d_in, const int* in_sizes, int n_in,
                              void* d_out, int out_size, void* d_ws, size_t ws_size,
                              hipStream_t stream) {
  const float* query  = (const float*)d_in[0];
  const float* memory = (const float*)d_in[1];
  const float* Wq = (const float*)d_in[2];
  const float* bq = (const float*)d_in[3];
  const float* Wk = (const float*)d_in[4];
  const float* bk = (const float*)d_in[5];
  const float* Wv = (const float*)d_in[6];
  const float* bv = (const float*)d_in[7];
  const float* Wo = (const float*)d_in[8];
  const float* bo = (const float*)d_in[9];
  const float* Wg = (const float*)d_in[10];
  const float* bg = (const float*)d_in[11];
  const float* usage = (const float*)d_in[12];

  float* out = (float*)d_out;
  float* retr_out = out;
  float* newmem = out + 131072;
  float* newusage = out + 131072 + 16777216;
  float* part2 = newmem;                                      // [64][512][256] f32 (32 MB)
  unsigned short* VT = (unsigned short*)(newmem + 8388608);   // [256][65536] bf16 (32 MB)

  float* ws = (float*)d_ws;
  float* Qb    = ws + OFF_Q;
  float* Gqb   = ws + OFF_GQ;
  float* Grb   = ws + OFF_GR;
  float* Rpreb = ws + OFF_RPRE;
  unsigned short* QBF   = (unsigned short*)(ws + OFF_QBF);
  unsigned short* WKBF  = (unsigned short*)(ws + OFF_WKBF);
  unsigned short* WVBF  = (unsigned short*)(ws + OFF_WVBF);
  unsigned short* KB    = (unsigned short*)(ws + OFF_KB);
  float* ZPb   = ws + OFF_ZP;
  float* AMVb  = ws + OFF_AMV;
  int*   AMIb  = (int*)(ws + OFF_AMI);
  int*   MXb   = (int*)(ws + OFF_MX);
  float* UMXb  = ws + OFF_UMX;
  float* CANDVb = ws + OFF_CANDV;
  int*   CANDIb = (int*)(ws + OFF_CANDI);
  float* BSUMb  = ws + OFF_BSUM;
  int*   CNTb   = (int*)(ws + OFF_CNT);
  int*   IDXAb  = (int*)(ws + OFF_IDXA);
  int*   CHAINb = (int*)(ws + OFF_CHAIN);

  // newusage copy depends only on inputs — run it first, fully overlapped
  hipMemcpyAsync(newusage, usage, (size_t)65536 * 4, hipMemcpyDeviceToDevice, stream);

  // weight cvt (Wk blocks 0..31, Wv 32..63) + CNT zeroing folded in
  k_cvt2<<<64, 256, 0, stream>>>(Wk, Wv, WKBF, WVBF, CNTb);
  // projmm (0..1023) || qgq (1024..1535)
  k_projq<<<1536, 256, 0, stream>>>(memory, WKBF, bk, WVBF, bv, KB, VT,
                                    query, Wq, bq, Wg, bg, Qb, Gqb, QBF);
  k_fused<<<dim3(64, 8), 256, 0, stream>>>(QBF, KB, VT, part2, ZPb, AMVb, AMIb);
  // amax2 (0..511) || cand (512..767) || rcomb+Z (768..1279)
  k_par0<<<1280, 256, 0, stream>>>(Qb, Wk, bk, memory, ZPb, AMVb, AMIb, usage,
                                   MXb, UMXb, CANDVb, CANDIb, CNTb, BSUMb,
                                   part2, Rpreb);
  // scan (0) || out1 (1..128) || full newmem copy (129..1152)
  k_par1<<<1153, 1024, 0, stream>>>(CANDVb, CANDIb, CNTb, BSUMb, MXb, UMXb, usage,
                                    IDXAb, CHAINb, newusage, Rpreb, Wo, bo, Wg,
                                    retr_out, Grb, memory, newmem);

  k_gate0<<<512, 256, 0, stream>>>(IDXAb, CHAINb, memory, query, Gqb, Grb, Wg, newmem);
  k_chain<<<512, 256, 0, stream>>>(IDXAb, CHAINb, query, Gqb, Grb, Wg, newmem);
}